// Round 12
// baseline (379.492 us; speedup 1.0000x reference)
//
#include <hip/hip_runtime.h>
#include <hip/hip_bf16.h>

// ConvTSP gated-GCN forward, MI355X (gfx950). Round 12.
// B=4, N=200, H=128, L=3. f32 in/out, x_edges int32.
//
// R11 post-mortem: (256,4)+rcpf both reverted (confounded, net -3.4%;
// rcpf doubles trans-pipe ops, (256,4) perturbs scheduling). 4x-confirmed
// law: k_edge is clean+fastest at (256,3)/VGPR48/IEEE-div = R9 config.
// R12 = R9 hot kernels byte-identical + dispatch-count cut 17 -> 11:
//  - k_pre: init_x + prep_w + cnt in one launch (grid 405).
//  - k_fin<DO_X>: xtmp + BN-N atomic sums (800x256 atomics, the R8-clean
//    pattern) + pS->BN-E reduction in blocks 0..31. Replaces k_xfin+k_red.

typedef __hip_bfloat16 bf16;
typedef __attribute__((ext_vector_type(8))) short short8_t;
typedef __attribute__((ext_vector_type(4))) float f32x4;

#define B_ 4
#define N_ 200
#define H_ 128
#define BN_ (B_ * N_)
#define JT_ 4
#define NBLK_ (BN_ * JT_)
#define MAXROWS_ 64

__device__ __forceinline__ unsigned short f2b(float f) {
  unsigned int i = __float_as_uint(f);
  i = (i + 0x7fffu + ((i >> 16) & 1u)) >> 16;  // RNE
  return (unsigned short)i;
}
__device__ __forceinline__ float b2f16(unsigned short u) {
  return __uint_as_float((unsigned int)u << 16);
}

// ---------------- fused prelude: init_x | prep_w | cnt ----------------

__global__ __launch_bounds__(256) void k_pre(
    const float* __restrict__ coord, const float* __restrict__ w_coord,
    const float* __restrict__ eUw, const float* __restrict__ mUw,
    const float* __restrict__ mask, float* __restrict__ x,
    bf16* __restrict__ WT, float* __restrict__ cnts) {
  int blk = blockIdx.x, t = threadIdx.x;
  if (blk < 400) {
    int bi = blk * 2 + (t >> 7), h = t & 127;
    float c0 = coord[bi * 2 + 0], c1 = coord[bi * 2 + 1];
    x[(size_t)bi * H_ + h] = c0 * w_coord[h] + c1 * w_coord[H_ + h];
  } else if (blk < 404) {
    int widx = blk - 400;
    const float* src = (widx < 3) ? (eUw + (size_t)widx * H_ * H_) : mUw;
    bf16* dst = WT + (size_t)widx * H_ * H_;
    for (int q = t; q < H_ * H_; q += 256) {
      int out = q >> 7, in = q & 127;
      dst[q] = __float2bfloat16(src[in * H_ + out]);
    }
  } else {
    int b = t >> 6, l = t & 63;
    float s = 0.f;
    for (int n = l; n < N_; n += 64) s += mask[b * N_ + n];
#pragma unroll
    for (int d = 1; d < 64; d <<= 1) s += __shfl_xor(s, d);
    __shared__ float ms[B_];
    if (l == 0) ms[b] = s;
    __syncthreads();
    if (t == 0) {
      float cn = 0.f, ce = 0.f;
      for (int k = 0; k < B_; ++k) { cn += ms[k]; ce += ms[k] * ms[k]; }
      cnts[0] = cn; cnts[1] = ce;
    }
  }
}

// ---------------- node linears (+fused x update, inline ssN) -------------

template <int UPD>
__global__ __launch_bounds__(128) void k_node_lin(
    float* __restrict__ x, const float* __restrict__ xtmp,
    const float* __restrict__ sumsPrev, const float* __restrict__ cnts,
    const float* __restrict__ gNp, const float* __restrict__ bNp,
    const float* __restrict__ eVw, const float* __restrict__ eVb,
    const float* __restrict__ nUw, const float* __restrict__ nUb,
    const float* __restrict__ nVw, const float* __restrict__ nVb,
    const float* __restrict__ mask, float* __restrict__ Vxe,
    float* __restrict__ Ux, float* __restrict__ Vx) {
  __shared__ float xr[H_];
  int bi = blockIdx.x, h = threadIdx.x;
  float m = mask[bi];
  float xv = x[(size_t)bi * H_ + h];
  if (UPD) {
    float cntN = cnts[0];
    float mN = sumsPrev[256 + h] / cntN;
    float vN = sumsPrev[384 + h] / cntN - mN * mN;
    float scN = gNp[h] * rsqrtf(vN + 1e-5f);
    float shN = bNp[h] - mN * scN;
    float tv = xtmp[(size_t)bi * H_ + h];
    float xn = (m > 0.f) ? fmaf(tv, scN, shN) : tv;
    xv += fmaxf(xn, 0.f);
    x[(size_t)bi * H_ + h] = xv;
  }
  xr[h] = xv;
  __syncthreads();
  float a = 0.f, bvv = 0.f, c = 0.f;
#pragma unroll 4
  for (int k = 0; k < H_; ++k) {
    float kx = xr[k];
    a   = fmaf(kx, eVw[k * H_ + h], a);
    bvv = fmaf(kx, nUw[k * H_ + h], bvv);
    c   = fmaf(kx, nVw[k * H_ + h], c);
  }
  Vxe[(size_t)bi * H_ + h] = m * (a + eVb[h]);
  Ux[(size_t)bi * H_ + h]  = m * (bvv + nUb[h]);
  Vx[(size_t)bi * H_ + h]  = m * (c + nVb[h]);
}

// ---------------- big kernel: staged-update + GEMM + epilogue ------------
// grid = BN_*JT_. blockIdx -> (bi, jh). Block owns j-tiles [mt0,mt1).
// MODE 0: layer 0. A = e0 from raw inputs. No e write.
// MODE 2: layer 1. A = e0(recomputed) + relu(bnE(etmp)). Writes e (bf16).
// MODE 1: layer 2. A = e + relu(bnE(etmp)); e updated in place.
// NO global atomics: per-block partials to pS / pAgg / pDen.

template <int MODE, bool DO_X>
__global__ __launch_bounds__(256, 3) void k_edge(
    bf16* __restrict__ e, bf16* __restrict__ etmp,
    const float* __restrict__ sumsPrev, const float* __restrict__ cnts,
    const float* __restrict__ gEp, const float* __restrict__ bEp,
    const int* __restrict__ xe, const float* __restrict__ ev,
    const float* __restrict__ w_eval, const float* __restrict__ emb,
    const bf16* __restrict__ WT, const float* __restrict__ eUb,
    const float* __restrict__ Vxe, const float* __restrict__ Vx,
    const float* __restrict__ mask, float* __restrict__ pS,
    float* __restrict__ pAgg, float* __restrict__ pDen) {
  __shared__ __align__(16) char sA[MAXROWS_ * 256];
  __shared__ float ssE_s[256];
  const int bi = blockIdx.x >> 2;
  const int jh = blockIdx.x & 3;
  const int mt0 = (jh == 0) ? 0 : 3 * jh + 1;
  const int mt1 = 3 * jh + 4;
  const int b = bi / N_;
  const int t = threadIdx.x;
  const int lane = t & 63;
  const int w = t >> 6;
  const float mask_i = mask[bi];

  // inline ssE from previous layer's sums (L2-hot, 2KB)
  if (MODE != 0) {
    int h = t & 127;
    float cntE = cnts[1];
    float mE = sumsPrev[h] / cntE;
    float vE = sumsPrev[128 + h] / cntE - mE * mE;
    float scE = gEp[h] * rsqrtf(vE + 1e-5f);
    ssE_s[t] = (t < 128) ? scE : (bEp[h] - mE * scE);
    __syncthreads();
  }

  // --- B fragments: named, no arrays ---
  const int colA = (w << 5) + (lane & 15);
  const int colB = colA + 16;
  const int kgrp = (lane >> 4) << 3;
  const short* wp0 = (const short*)WT + colA * H_ + kgrp;
  const short* wp1 = (const short*)WT + colB * H_ + kgrp;
  short8_t bfA0 = *(const short8_t*)(wp0);
  short8_t bfA1 = *(const short8_t*)(wp0 + 32);
  short8_t bfA2 = *(const short8_t*)(wp0 + 64);
  short8_t bfA3 = *(const short8_t*)(wp0 + 96);
  short8_t bfB0 = *(const short8_t*)(wp1);
  short8_t bfB1 = *(const short8_t*)(wp1 + 32);
  short8_t bfB2 = *(const short8_t*)(wp1 + 64);
  short8_t bfB3 = *(const short8_t*)(wp1 + 96);

  // --- staging: rows [mt0*16, mt1*16), 8B granule, named scalars ---
  {
    const int nrt = (mt1 - mt0) << 4;  // 48 or 64 rows
    unsigned short* eb = (unsigned short*)e + (size_t)bi * N_ * H_;
    const unsigned short* tb =
        (const unsigned short*)etmp + (size_t)bi * N_ * H_;
    for (int q4 = t; q4 < nrt * 32; q4 += 256) {
      int lr = q4 >> 5, k0 = (q4 & 31) << 2;
      int row = (mt0 << 4) + lr;
      float v0 = 0.f, v1 = 0.f, v2 = 0.f, v3 = 0.f;
      if (row < N_) {
        if (MODE == 0 || MODE == 2) {
          if (k0 < 64) {
            float evv = ev[bi * N_ + row];
            float4 we = *(const float4*)(w_eval + k0);
            v0 = evv * we.x; v1 = evv * we.y;
            v2 = evv * we.z; v3 = evv * we.w;
          } else {
            float4 em4 = *(const float4*)(emb + xe[bi * N_ + row] * 64 + (k0 - 64));
            v0 = em4.x; v1 = em4.y; v2 = em4.z; v3 = em4.w;
          }
        } else {
          ushort4 e4 = *(const ushort4*)(eb + row * H_ + k0);
          v0 = b2f16(e4.x); v1 = b2f16(e4.y);
          v2 = b2f16(e4.z); v3 = b2f16(e4.w);
        }
        if (MODE != 0) {
          ushort4 t4 = *(const ushort4*)(tb + row * H_ + k0);
          float mj = mask[b * N_ + row];
          bool msk = (mask_i * mj) > 0.f;
          float sc0 = ssE_s[k0 + 0], sc1 = ssE_s[k0 + 1];
          float sc2 = ssE_s[k0 + 2], sc3 = ssE_s[k0 + 3];
          float sh0 = ssE_s[128 + k0 + 0], sh1 = ssE_s[128 + k0 + 1];
          float sh2 = ssE_s[128 + k0 + 2], sh3 = ssE_s[128 + k0 + 3];
          float f0 = b2f16(t4.x), f1 = b2f16(t4.y);
          float f2 = b2f16(t4.z), f3 = b2f16(t4.w);
          v0 += fmaxf(msk ? fmaf(f0, sc0, sh0) : f0, 0.f);
          v1 += fmaxf(msk ? fmaf(f1, sc1, sh1) : f1, 0.f);
          v2 += fmaxf(msk ? fmaf(f2, sc2, sh2) : f2, 0.f);
          v3 += fmaxf(msk ? fmaf(f3, sc3, sh3) : f3, 0.f);
        }
      }
      unsigned int p0 = ((unsigned int)f2b(v1) << 16) | f2b(v0);
      unsigned int p1 = ((unsigned int)f2b(v3) << 16) | f2b(v2);
      if (MODE != 0 && row < N_)
        *(uint2*)(eb + row * H_ + k0) = make_uint2(p0, p1);  // persist e_l
      unsigned long long pk = ((unsigned long long)p1 << 32) | p0;
      int byo = (lr << 8) + ((k0 * 2) ^ ((lr & 7) << 4));
      *(unsigned long long*)(sA + byo) = pk;
    }
  }
  __syncthreads();

  // --- GEMM + gate/agg/BN epilogue (R8 shape, no arrays) ---
  const float add0 = eUb[colA] + Vxe[(size_t)bi * H_ + colA];
  const float add1 = eUb[colB] + Vxe[(size_t)bi * H_ + colB];
  const float* VxeB = Vxe + (size_t)b * N_ * H_;
  const float* VxB  = Vx  + (size_t)b * N_ * H_;

  float agg0 = 0.f, agg1 = 0.f, den0 = 0.f, den1 = 0.f;
  float s1a = 0.f, s1b = 0.f, s2a = 0.f, s2b = 0.f;
  const int kb = (lane >> 4) << 4;

  for (int mt = mt0; mt < mt1; ++mt) {
    f32x4 acc0 = {0.f, 0.f, 0.f, 0.f}, acc1 = {0.f, 0.f, 0.f, 0.f};
    int ra = ((mt - mt0) << 4) + (lane & 15);
    const char* ap = sA + (ra << 8);
    int sw = (ra & 7) << 4;
    short8_t av;
    av = *(const short8_t*)(ap + ((kb + 0) ^ sw));
    acc0 = __builtin_amdgcn_mfma_f32_16x16x32_bf16(av, bfA0, acc0, 0, 0, 0);
    acc1 = __builtin_amdgcn_mfma_f32_16x16x32_bf16(av, bfB0, acc1, 0, 0, 0);
    av = *(const short8_t*)(ap + ((kb + 64) ^ sw));
    acc0 = __builtin_amdgcn_mfma_f32_16x16x32_bf16(av, bfA1, acc0, 0, 0, 0);
    acc1 = __builtin_amdgcn_mfma_f32_16x16x32_bf16(av, bfB1, acc1, 0, 0, 0);
    av = *(const short8_t*)(ap + ((kb + 128) ^ sw));
    acc0 = __builtin_amdgcn_mfma_f32_16x16x32_bf16(av, bfA2, acc0, 0, 0, 0);
    acc1 = __builtin_amdgcn_mfma_f32_16x16x32_bf16(av, bfB2, acc1, 0, 0, 0);
    av = *(const short8_t*)(ap + ((kb + 192) ^ sw));
    acc0 = __builtin_amdgcn_mfma_f32_16x16x32_bf16(av, bfA3, acc0, 0, 0, 0);
    acc1 = __builtin_amdgcn_mfma_f32_16x16x32_bf16(av, bfB3, acc1, 0, 0, 0);
#pragma unroll
    for (int r = 0; r < 4; ++r) {
      int j = (mt << 4) + ((lane >> 4) << 2) + r;
      bool valid = (j < N_);
      float mj = valid ? mask[b * N_ + j] : 0.f;
      float sqm = mask_i * mj;
      float vj0 = valid ? VxeB[(size_t)j * H_ + colA] : 0.f;
      float vj1 = valid ? VxeB[(size_t)j * H_ + colB] : 0.f;
      float t0 = acc0[r] + add0 + vj0;
      float t1 = acc1[r] + add1 + vj1;
      if (valid) {
        size_t o = ((size_t)bi * N_ + j) * H_;
        ((unsigned short*)etmp)[o + colA] = f2b(t0);
        ((unsigned short*)etmp)[o + colB] = f2b(t1);
      }
      float g0 = sqm / (1.f + __expf(-t0));
      float g1 = sqm / (1.f + __expf(-t1));
      float vx0 = valid ? VxB[(size_t)j * H_ + colA] : 0.f;
      float vx1 = valid ? VxB[(size_t)j * H_ + colB] : 0.f;
      agg0 = fmaf(g0, vx0, agg0);
      agg1 = fmaf(g1, vx1, agg1);
      den0 += g0; den1 += g1;
      s1a = fmaf(t0, sqm, s1a);
      s1b = fmaf(t1, sqm, s1b);
      s2a = fmaf(t0 * sqm, t0, s2a);
      s2b = fmaf(t1 * sqm, t1, s2b);
    }
  }
#pragma unroll
  for (int d = 16; d <= 32; d <<= 1) {
    agg0 += __shfl_xor(agg0, d); agg1 += __shfl_xor(agg1, d);
    den0 += __shfl_xor(den0, d); den1 += __shfl_xor(den1, d);
    s1a += __shfl_xor(s1a, d);   s1b += __shfl_xor(s1b, d);
    s2a += __shfl_xor(s2a, d);   s2b += __shfl_xor(s2b, d);
  }
  if ((lane >> 4) == 0) {
    float* ps = pS + (size_t)blockIdx.x * 256;
    ps[colA] = s1a;
    ps[colB] = s1b;
    ps[128 + colA] = s2a;
    ps[128 + colB] = s2b;
    if (DO_X) {
      size_t po = ((size_t)jh * BN_ + bi) * H_;
      pAgg[po + colA] = agg0;
      pAgg[po + colB] = agg1;
      pDen[po + colA] = den0;
      pDen[po + colB] = den1;
    }
  }
}

// ---------------- fused finalize: xtmp + BN-N sums + pS reduction --------
// DO_X=1: grid 800, 128 thr. Per-bi xtmp + BN-N atomics; blocks 0..31 also
//         reduce their pS slice into sums (BN-E).
// DO_X=0: grid 32, 128 thr. pS reduction only (layer 2).

template <bool DO_X>
__global__ __launch_bounds__(128) void k_fin(
    const float* __restrict__ pAgg, const float* __restrict__ pDen,
    const float* __restrict__ pS, const float* __restrict__ Ux,
    const float* __restrict__ mask, float* __restrict__ xtmp,
    float* __restrict__ sums) {
  int bi = blockIdx.x, h = threadIdx.x;
  if (DO_X) {
    float a0 = pAgg[(size_t)bi * H_ + h];
    float a1 = pAgg[((size_t)BN_ + bi) * H_ + h];
    float a2 = pAgg[((size_t)2 * BN_ + bi) * H_ + h];
    float a3 = pAgg[((size_t)3 * BN_ + bi) * H_ + h];
    float d0 = pDen[(size_t)bi * H_ + h];
    float d1 = pDen[((size_t)BN_ + bi) * H_ + h];
    float d2 = pDen[((size_t)2 * BN_ + bi) * H_ + h];
    float d3 = pDen[((size_t)3 * BN_ + bi) * H_ + h];
    float a = (a0 + a1) + (a2 + a3);
    float d = (d0 + d1) + (d2 + d3);
    float xt = Ux[(size_t)bi * H_ + h] + a / (1e-20f + d);
    xtmp[(size_t)bi * H_ + h] = xt;
    float mi = mask[bi];
    atomicAdd(&sums[256 + h], xt * mi);
    atomicAdd(&sums[384 + h], xt * xt * mi);
  }
  if (bi < 32) {
    float acc0 = 0.f, acc1 = 0.f;
    for (int blk = bi * (NBLK_ / 32); blk < (bi + 1) * (NBLK_ / 32); ++blk) {
      acc0 += pS[(size_t)blk * 256 + h];
      acc1 += pS[(size_t)blk * 256 + 128 + h];
    }
    atomicAdd(&sums[h], acc0);
    atomicAdd(&sums[128 + h], acc1);
  }
}

// ---------------- head: A = e + relu(bnE(etmp)); y = relu(A@U+bU)@V + bV --

__global__ __launch_bounds__(256, 3) void k_head(
    const bf16* __restrict__ e, const bf16* __restrict__ etmp,
    const float* __restrict__ sumsPrev, const float* __restrict__ cnts,
    const float* __restrict__ gEp, const float* __restrict__ bEp,
    const bf16* __restrict__ UT, const float* __restrict__ Ub,
    const float* __restrict__ Vw, const float* __restrict__ Vb,
    const float* __restrict__ mask, float* __restrict__ y) {
  __shared__ __align__(16) char sA[MAXROWS_ * 256];
  __shared__ float part[4][MAXROWS_][2];
  __shared__ float ssE_s[256];
  const int bi = blockIdx.x >> 2;
  const int jh = blockIdx.x & 3;
  const int mt0 = (jh == 0) ? 0 : 3 * jh + 1;
  const int mt1 = 3 * jh + 4;
  const int b = bi / N_;
  const int t = threadIdx.x;
  const int lane = t & 63;
  const int w = t >> 6;
  const float mask_i = mask[bi];

  {
    int h = t & 127;
    float cntE = cnts[1];
    float mE = sumsPrev[h] / cntE;
    float vE = sumsPrev[128 + h] / cntE - mE * mE;
    float scE = gEp[h] * rsqrtf(vE + 1e-5f);
    ssE_s[t] = (t < 128) ? scE : (bEp[h] - mE * scE);
    __syncthreads();
  }

  const int colA = (w << 5) + (lane & 15);
  const int colB = colA + 16;
  const int kgrp = (lane >> 4) << 3;
  const short* wp0 = (const short*)UT + colA * H_ + kgrp;
  const short* wp1 = (const short*)UT + colB * H_ + kgrp;
  short8_t bfA0 = *(const short8_t*)(wp0);
  short8_t bfA1 = *(const short8_t*)(wp0 + 32);
  short8_t bfA2 = *(const short8_t*)(wp0 + 64);
  short8_t bfA3 = *(const short8_t*)(wp0 + 96);
  short8_t bfB0 = *(const short8_t*)(wp1);
  short8_t bfB1 = *(const short8_t*)(wp1 + 32);
  short8_t bfB2 = *(const short8_t*)(wp1 + 64);
  short8_t bfB3 = *(const short8_t*)(wp1 + 96);

  {
    const int nrt = (mt1 - mt0) << 4;
    const unsigned short* eb = (const unsigned short*)e + (size_t)bi * N_ * H_;
    const unsigned short* tb =
        (const unsigned short*)etmp + (size_t)bi * N_ * H_;
    for (int q4 = t; q4 < nrt * 32; q4 += 256) {
      int lr = q4 >> 5, k0 = (q4 & 31) << 2;
      int row = (mt0 << 4) + lr;
      float v0 = 0.f, v1 = 0.f, v2 = 0.f, v3 = 0.f;
      if (row < N_) {
        ushort4 e4 = *(const ushort4*)(eb + row * H_ + k0);
        ushort4 t4 = *(const ushort4*)(tb + row * H_ + k0);
        float mj = mask[b * N_ + row];
        bool msk = (mask_i * mj) > 0.f;
        float sc0 = ssE_s[k0 + 0], sc1 = ssE_s[k0 + 1];
        float sc2 = ssE_s[k0 + 2], sc3 = ssE_s[k0 + 3];
        float sh0 = ssE_s[128 + k0 + 0], sh1 = ssE_s[128 + k0 + 1];
        float sh2 = ssE_s[128 + k0 + 2], sh3 = ssE_s[128 + k0 + 3];
        float f0 = b2f16(t4.x), f1 = b2f16(t4.y);
        float f2 = b2f16(t4.z), f3 = b2f16(t4.w);
        v0 = b2f16(e4.x) + fmaxf(msk ? fmaf(f0, sc0, sh0) : f0, 0.f);
        v1 = b2f16(e4.y) + fmaxf(msk ? fmaf(f1, sc1, sh1) : f1, 0.f);
        v2 = b2f16(e4.z) + fmaxf(msk ? fmaf(f2, sc2, sh2) : f2, 0.f);
        v3 = b2f16(e4.w) + fmaxf(msk ? fmaf(f3, sc3, sh3) : f3, 0.f);
      }
      unsigned int p0 = ((unsigned int)f2b(v1) << 16) | f2b(v0);
      unsigned int p1 = ((unsigned int)f2b(v3) << 16) | f2b(v2);
      unsigned long long pk = ((unsigned long long)p1 << 32) | p0;
      int byo = (lr << 8) + ((k0 * 2) ^ ((lr & 7) << 4));
      *(unsigned long long*)(sA + byo) = pk;
    }
  }
  __syncthreads();

  float bu0 = Ub[colA], bu1 = Ub[colB];
  float v00 = Vw[colA * 2], v01 = Vw[colA * 2 + 1];
  float v10 = Vw[colB * 2], v11 = Vw[colB * 2 + 1];
  const int kb = (lane >> 4) << 4;

  for (int mt = mt0; mt < mt1; ++mt) {
    f32x4 acc0 = {0.f, 0.f, 0.f, 0.f}, acc1 = {0.f, 0.f, 0.f, 0.f};
    int ra = ((mt - mt0) << 4) + (lane & 15);
    const char* ap = sA + (ra << 8);
    int sw = (ra & 7) << 4;
    short8_t av;
    av = *(const short8_t*)(ap + ((kb + 0) ^ sw));
    acc0 = __builtin_amdgcn_mfma_f32_16x16x32_bf16(av, bfA0, acc0, 0, 0, 0);
    acc1 = __builtin_amdgcn_mfma_f32_16x16x32_bf16(av, bfB0, acc1, 0, 0, 0);
    av = *(const short8_t*)(ap + ((kb + 64) ^ sw));
    acc0 = __builtin_amdgcn_mfma_f32_16x16x32_bf16(av, bfA1, acc0, 0, 0, 0);
    acc1 = __builtin_amdgcn_mfma_f32_16x16x32_bf16(av, bfB1, acc1, 0, 0, 0);
    av = *(const short8_t*)(ap + ((kb + 128) ^ sw));
    acc0 = __builtin_amdgcn_mfma_f32_16x16x32_bf16(av, bfA2, acc0, 0, 0, 0);
    acc1 = __builtin_amdgcn_mfma_f32_16x16x32_bf16(av, bfB2, acc1, 0, 0, 0);
    av = *(const short8_t*)(ap + ((kb + 192) ^ sw));
    acc0 = __builtin_amdgcn_mfma_f32_16x16x32_bf16(av, bfA3, acc0, 0, 0, 0);
    acc1 = __builtin_amdgcn_mfma_f32_16x16x32_bf16(av, bfB3, acc1, 0, 0, 0);
#pragma unroll
    for (int r = 0; r < 4; ++r) {
      float h0v = fmaxf(acc0[r] + bu0, 0.f);
      float h1v = fmaxf(acc1[r] + bu1, 0.f);
      float p0 = h0v * v00 + h1v * v10;
      float p1 = h0v * v01 + h1v * v11;
#pragma unroll
      for (int d = 1; d < 16; d <<= 1) {
        p0 += __shfl_xor(p0, d);
        p1 += __shfl_xor(p1, d);
      }
      int jl = ((mt - mt0) << 4) + ((lane >> 4) << 2) + r;
      if ((lane & 15) == 0) { part[w][jl][0] = p0; part[w][jl][1] = p1; }
    }
  }
  __syncthreads();
  float vb0 = Vb[0], vb1 = Vb[1];
  const int nrt = (mt1 - mt0) << 4;
  for (int q = t; q < nrt * 2; q += 256) {
    int jl = q >> 1, c = q & 1;
    int j = (mt0 << 4) + jl;
    if (j < N_) {
      float s = part[0][jl][c] + part[1][jl][c] + part[2][jl][c] +
                part[3][jl][c] + (c ? vb1 : vb0);
      y[((size_t)bi * N_ + j) * 2 + c] = s;
    }
  }
}

// ---------------- launch ----------------

extern "C" void kernel_launch(void* const* d_in, const int* in_sizes, int n_in,
                              void* d_out, int out_size, void* d_ws,
                              size_t ws_size, hipStream_t stream) {
  const int*   x_edges = (const int*)d_in[0];
  const float* ev      = (const float*)d_in[1];
  const float* coord   = (const float*)d_in[2];
  const float* mask    = (const float*)d_in[3];
  const float* w_coord = (const float*)d_in[4];
  const float* w_eval  = (const float*)d_in[5];
  const float* emb     = (const float*)d_in[6];
  const float* eUw = (const float*)d_in[7];
  const float* eUb = (const float*)d_in[8];
  const float* eVw = (const float*)d_in[9];
  const float* eVb = (const float*)d_in[10];
  const float* nUw = (const float*)d_in[11];
  const float* nUb = (const float*)d_in[12];
  const float* nVw = (const float*)d_in[13];
  const float* nVb = (const float*)d_in[14];
  const float* gE  = (const float*)d_in[15];
  const float* bE  = (const float*)d_in[16];
  const float* gN  = (const float*)d_in[17];
  const float* bN  = (const float*)d_in[18];
  const float* mUw = (const float*)d_in[19];
  const float* mUb = (const float*)d_in[20];
  const float* mVw = (const float*)d_in[21];
  const float* mVb = (const float*)d_in[22];

  char* ws = (char*)d_ws;
  size_t off = 0;
  auto alloc = [&](size_t bytes) {
    void* p = ws + off;
    off += (bytes + 255) & ~(size_t)255;
    return p;
  };
  bf16* e     = (bf16*)alloc((size_t)B_ * N_ * N_ * H_ * 2);   // 40.96 MB
  bf16* etmp  = (bf16*)alloc((size_t)B_ * N_ * N_ * H_ * 2);   // 40.96 MB
  float* x    = (float*)alloc((size_t)BN_ * H_ * 4);
  float* Vxe  = (float*)alloc((size_t)BN_ * H_ * 4);
  float* Ux   = (float*)alloc((size_t)BN_ * H_ * 4);
  float* Vx   = (float*)alloc((size_t)BN_ * H_ * 4);
  float* xtmp = (float*)alloc((size_t)BN_ * H_ * 4);
  float* pS   = (float*)alloc((size_t)NBLK_ * 256 * 4);        // 3.28 MB
  float* pAgg = (float*)alloc((size_t)JT_ * BN_ * H_ * 4);     // 1.64 MB
  float* pDen = (float*)alloc((size_t)JT_ * BN_ * H_ * 4);     // 1.64 MB
  float* sums = (float*)alloc(3 * 512 * 4);  // 3 layers x [s1E,s2E,s1N,s2N]
  float* cnts = (float*)alloc(256);
  bf16* WT    = (bf16*)alloc((size_t)4 * H_ * H_ * 2);

  hipMemsetAsync(sums, 0, 3 * 512 * 4, stream);
  k_pre<<<405, 256, 0, stream>>>(coord, w_coord, eUw, mUw, mask, x, WT, cnts);

  float* sums0 = sums;
  float* sums1 = sums + 512;
  float* sums2 = sums + 1024;

  // layer 0
  k_node_lin<0><<<BN_, 128, 0, stream>>>(
      x, xtmp, sums0, cnts, gN, bN, eVw, eVb, nUw, nUb, nVw, nVb, mask, Vxe,
      Ux, Vx);
  k_edge<0, true><<<NBLK_, 256, 0, stream>>>(
      e, etmp, sums0, cnts, gE, bE, x_edges, ev, w_eval, emb, WT, eUb, Vxe,
      Vx, mask, pS, pAgg, pDen);
  k_fin<true><<<BN_, 128, 0, stream>>>(pAgg, pDen, pS, Ux, mask, xtmp, sums0);
  // layer 1
  k_node_lin<1><<<BN_, 128, 0, stream>>>(
      x, xtmp, sums0, cnts, gN, bN, eVw + H_ * H_, eVb + H_, nUw + H_ * H_,
      nUb + H_, nVw + H_ * H_, nVb + H_, mask, Vxe, Ux, Vx);
  k_edge<2, true><<<NBLK_, 256, 0, stream>>>(
      e, etmp, sums0, cnts, gE, bE, x_edges, ev, w_eval, emb, WT + H_ * H_,
      eUb + H_, Vxe, Vx, mask, pS, pAgg, pDen);
  k_fin<true><<<BN_, 128, 0, stream>>>(pAgg, pDen, pS, Ux, mask, xtmp, sums1);
  // layer 2
  k_node_lin<1><<<BN_, 128, 0, stream>>>(
      x, xtmp, sums1, cnts, gN + H_, bN + H_, eVw + 2 * H_ * H_,
      eVb + 2 * H_, nUw + 2 * H_ * H_, nUb + 2 * H_, nVw + 2 * H_ * H_,
      nVb + 2 * H_, mask, Vxe, Ux, Vx);
  k_edge<1, false><<<NBLK_, 256, 0, stream>>>(
      e, etmp, sums1, cnts, gE + H_, bE + H_, x_edges, ev, w_eval, emb,
      WT + 2 * H_ * H_, eUb + 2 * H_, Vxe, Vx, mask, pS, pAgg, pDen);
  k_fin<false><<<32, 128, 0, stream>>>(pAgg, pDen, pS, Ux, mask, xtmp, sums2);
  // head
  k_head<<<NBLK_, 256, 0, stream>>>(e, etmp, sums2, cnts, gE + 2 * H_,
                                    bE + 2 * H_, WT + (size_t)3 * H_ * H_,
                                    mUb, mVw, mVb, mask, (float*)d_out);
}

// Round 13
// 342.609 us; speedup vs baseline: 1.1077x; 1.1077x over previous
//
#include <hip/hip_runtime.h>
#include <hip/hip_bf16.h>

// ConvTSP gated-GCN forward, MI355X (gfx950). Round 13.
// B=4, N=200, H=128, L=3. f32 in/out, x_edges int32.
//
// R12 post-mortem: fused k_fin regressed +33us — 800 blocks x 256 atomics
// onto the SAME 256 addresses = 800 serialized RMWs/address (~16us/layer).
// R9's two-stage reduction (k_xfin contention-free stores + k_red 32
// adds/address) was right. R13 = exact R9 kernel set (4x-validated optimum:
// (256,3)/VGPR48/IEEE-div/two-stage reductions) + R12's k_pre only
// (one-time prelude fusion, no atomics).

typedef __hip_bfloat16 bf16;
typedef __attribute__((ext_vector_type(8))) short short8_t;
typedef __attribute__((ext_vector_type(4))) float f32x4;

#define B_ 4
#define N_ 200
#define H_ 128
#define BN_ (B_ * N_)
#define JT_ 4
#define NBLK_ (BN_ * JT_)
#define MAXROWS_ 64

__device__ __forceinline__ unsigned short f2b(float f) {
  unsigned int i = __float_as_uint(f);
  i = (i + 0x7fffu + ((i >> 16) & 1u)) >> 16;  // RNE
  return (unsigned short)i;
}
__device__ __forceinline__ float b2f16(unsigned short u) {
  return __uint_as_float((unsigned int)u << 16);
}

// ---------------- fused prelude: init_x | prep_w | cnt ----------------

__global__ __launch_bounds__(256) void k_pre(
    const float* __restrict__ coord, const float* __restrict__ w_coord,
    const float* __restrict__ eUw, const float* __restrict__ mUw,
    const float* __restrict__ mask, float* __restrict__ x,
    bf16* __restrict__ WT, float* __restrict__ cnts) {
  int blk = blockIdx.x, t = threadIdx.x;
  if (blk < 400) {
    int bi = blk * 2 + (t >> 7), h = t & 127;
    float c0 = coord[bi * 2 + 0], c1 = coord[bi * 2 + 1];
    x[(size_t)bi * H_ + h] = c0 * w_coord[h] + c1 * w_coord[H_ + h];
  } else if (blk < 404) {
    int widx = blk - 400;
    const float* src = (widx < 3) ? (eUw + (size_t)widx * H_ * H_) : mUw;
    bf16* dst = WT + (size_t)widx * H_ * H_;
    for (int q = t; q < H_ * H_; q += 256) {
      int out = q >> 7, in = q & 127;
      dst[q] = __float2bfloat16(src[in * H_ + out]);
    }
  } else {
    int b = t >> 6, l = t & 63;
    float s = 0.f;
    for (int n = l; n < N_; n += 64) s += mask[b * N_ + n];
#pragma unroll
    for (int d = 1; d < 64; d <<= 1) s += __shfl_xor(s, d);
    __shared__ float ms[B_];
    if (l == 0) ms[b] = s;
    __syncthreads();
    if (t == 0) {
      float cn = 0.f, ce = 0.f;
      for (int k = 0; k < B_; ++k) { cn += ms[k]; ce += ms[k] * ms[k]; }
      cnts[0] = cn; cnts[1] = ce;
    }
  }
}

// ---------------- node linears (+fused x update, inline ssN) -------------

template <int UPD>
__global__ __launch_bounds__(128) void k_node_lin(
    float* __restrict__ x, const float* __restrict__ xtmp,
    const float* __restrict__ sumsPrev, const float* __restrict__ cnts,
    const float* __restrict__ gNp, const float* __restrict__ bNp,
    const float* __restrict__ eVw, const float* __restrict__ eVb,
    const float* __restrict__ nUw, const float* __restrict__ nUb,
    const float* __restrict__ nVw, const float* __restrict__ nVb,
    const float* __restrict__ mask, float* __restrict__ Vxe,
    float* __restrict__ Ux, float* __restrict__ Vx) {
  __shared__ float xr[H_];
  int bi = blockIdx.x, h = threadIdx.x;
  float m = mask[bi];
  float xv = x[(size_t)bi * H_ + h];
  if (UPD) {
    float cntN = cnts[0];
    float mN = sumsPrev[256 + h] / cntN;
    float vN = sumsPrev[384 + h] / cntN - mN * mN;
    float scN = gNp[h] * rsqrtf(vN + 1e-5f);
    float shN = bNp[h] - mN * scN;
    float tv = xtmp[(size_t)bi * H_ + h];
    float xn = (m > 0.f) ? fmaf(tv, scN, shN) : tv;
    xv += fmaxf(xn, 0.f);
    x[(size_t)bi * H_ + h] = xv;
  }
  xr[h] = xv;
  __syncthreads();
  float a = 0.f, bvv = 0.f, c = 0.f;
#pragma unroll 4
  for (int k = 0; k < H_; ++k) {
    float kx = xr[k];
    a   = fmaf(kx, eVw[k * H_ + h], a);
    bvv = fmaf(kx, nUw[k * H_ + h], bvv);
    c   = fmaf(kx, nVw[k * H_ + h], c);
  }
  Vxe[(size_t)bi * H_ + h] = m * (a + eVb[h]);
  Ux[(size_t)bi * H_ + h]  = m * (bvv + nUb[h]);
  Vx[(size_t)bi * H_ + h]  = m * (c + nVb[h]);
}

// ---------------- big kernel: staged-update + GEMM + epilogue ------------
// grid = BN_*JT_. blockIdx -> (bi, jh). Block owns j-tiles [mt0,mt1).
// MODE 0: layer 0. A = e0 from raw inputs. No e write.
// MODE 2: layer 1. A = e0(recomputed) + relu(bnE(etmp)). Writes e (bf16).
// MODE 1: layer 2. A = e + relu(bnE(etmp)); e updated in place.
// NO global atomics: per-block partials to pS / pAgg / pDen.

template <int MODE, bool DO_X>
__global__ __launch_bounds__(256, 3) void k_edge(
    bf16* __restrict__ e, bf16* __restrict__ etmp,
    const float* __restrict__ sumsPrev, const float* __restrict__ cnts,
    const float* __restrict__ gEp, const float* __restrict__ bEp,
    const int* __restrict__ xe, const float* __restrict__ ev,
    const float* __restrict__ w_eval, const float* __restrict__ emb,
    const bf16* __restrict__ WT, const float* __restrict__ eUb,
    const float* __restrict__ Vxe, const float* __restrict__ Vx,
    const float* __restrict__ mask, float* __restrict__ pS,
    float* __restrict__ pAgg, float* __restrict__ pDen) {
  __shared__ __align__(16) char sA[MAXROWS_ * 256];
  __shared__ float ssE_s[256];
  const int bi = blockIdx.x >> 2;
  const int jh = blockIdx.x & 3;
  const int mt0 = (jh == 0) ? 0 : 3 * jh + 1;
  const int mt1 = 3 * jh + 4;
  const int b = bi / N_;
  const int t = threadIdx.x;
  const int lane = t & 63;
  const int w = t >> 6;
  const float mask_i = mask[bi];

  // inline ssE from previous layer's sums (L2-hot, 2KB)
  if (MODE != 0) {
    int h = t & 127;
    float cntE = cnts[1];
    float mE = sumsPrev[h] / cntE;
    float vE = sumsPrev[128 + h] / cntE - mE * mE;
    float scE = gEp[h] * rsqrtf(vE + 1e-5f);
    ssE_s[t] = (t < 128) ? scE : (bEp[h] - mE * scE);
    __syncthreads();
  }

  // --- B fragments: named, no arrays ---
  const int colA = (w << 5) + (lane & 15);
  const int colB = colA + 16;
  const int kgrp = (lane >> 4) << 3;
  const short* wp0 = (const short*)WT + colA * H_ + kgrp;
  const short* wp1 = (const short*)WT + colB * H_ + kgrp;
  short8_t bfA0 = *(const short8_t*)(wp0);
  short8_t bfA1 = *(const short8_t*)(wp0 + 32);
  short8_t bfA2 = *(const short8_t*)(wp0 + 64);
  short8_t bfA3 = *(const short8_t*)(wp0 + 96);
  short8_t bfB0 = *(const short8_t*)(wp1);
  short8_t bfB1 = *(const short8_t*)(wp1 + 32);
  short8_t bfB2 = *(const short8_t*)(wp1 + 64);
  short8_t bfB3 = *(const short8_t*)(wp1 + 96);

  // --- staging: rows [mt0*16, mt1*16), 8B granule, named scalars ---
  {
    const int nrt = (mt1 - mt0) << 4;  // 48 or 64 rows
    unsigned short* eb = (unsigned short*)e + (size_t)bi * N_ * H_;
    const unsigned short* tb =
        (const unsigned short*)etmp + (size_t)bi * N_ * H_;
    for (int q4 = t; q4 < nrt * 32; q4 += 256) {
      int lr = q4 >> 5, k0 = (q4 & 31) << 2;
      int row = (mt0 << 4) + lr;
      float v0 = 0.f, v1 = 0.f, v2 = 0.f, v3 = 0.f;
      if (row < N_) {
        if (MODE == 0 || MODE == 2) {
          if (k0 < 64) {
            float evv = ev[bi * N_ + row];
            float4 we = *(const float4*)(w_eval + k0);
            v0 = evv * we.x; v1 = evv * we.y;
            v2 = evv * we.z; v3 = evv * we.w;
          } else {
            float4 em4 = *(const float4*)(emb + xe[bi * N_ + row] * 64 + (k0 - 64));
            v0 = em4.x; v1 = em4.y; v2 = em4.z; v3 = em4.w;
          }
        } else {
          ushort4 e4 = *(const ushort4*)(eb + row * H_ + k0);
          v0 = b2f16(e4.x); v1 = b2f16(e4.y);
          v2 = b2f16(e4.z); v3 = b2f16(e4.w);
        }
        if (MODE != 0) {
          ushort4 t4 = *(const ushort4*)(tb + row * H_ + k0);
          float mj = mask[b * N_ + row];
          bool msk = (mask_i * mj) > 0.f;
          float sc0 = ssE_s[k0 + 0], sc1 = ssE_s[k0 + 1];
          float sc2 = ssE_s[k0 + 2], sc3 = ssE_s[k0 + 3];
          float sh0 = ssE_s[128 + k0 + 0], sh1 = ssE_s[128 + k0 + 1];
          float sh2 = ssE_s[128 + k0 + 2], sh3 = ssE_s[128 + k0 + 3];
          float f0 = b2f16(t4.x), f1 = b2f16(t4.y);
          float f2 = b2f16(t4.z), f3 = b2f16(t4.w);
          v0 += fmaxf(msk ? fmaf(f0, sc0, sh0) : f0, 0.f);
          v1 += fmaxf(msk ? fmaf(f1, sc1, sh1) : f1, 0.f);
          v2 += fmaxf(msk ? fmaf(f2, sc2, sh2) : f2, 0.f);
          v3 += fmaxf(msk ? fmaf(f3, sc3, sh3) : f3, 0.f);
        }
      }
      unsigned int p0 = ((unsigned int)f2b(v1) << 16) | f2b(v0);
      unsigned int p1 = ((unsigned int)f2b(v3) << 16) | f2b(v2);
      if (MODE != 0 && row < N_)
        *(uint2*)(eb + row * H_ + k0) = make_uint2(p0, p1);  // persist e_l
      unsigned long long pk = ((unsigned long long)p1 << 32) | p0;
      int byo = (lr << 8) + ((k0 * 2) ^ ((lr & 7) << 4));
      *(unsigned long long*)(sA + byo) = pk;
    }
  }
  __syncthreads();

  // --- GEMM + gate/agg/BN epilogue (R8 shape, no arrays) ---
  const float add0 = eUb[colA] + Vxe[(size_t)bi * H_ + colA];
  const float add1 = eUb[colB] + Vxe[(size_t)bi * H_ + colB];
  const float* VxeB = Vxe + (size_t)b * N_ * H_;
  const float* VxB  = Vx  + (size_t)b * N_ * H_;

  float agg0 = 0.f, agg1 = 0.f, den0 = 0.f, den1 = 0.f;
  float s1a = 0.f, s1b = 0.f, s2a = 0.f, s2b = 0.f;
  const int kb = (lane >> 4) << 4;

  for (int mt = mt0; mt < mt1; ++mt) {
    f32x4 acc0 = {0.f, 0.f, 0.f, 0.f}, acc1 = {0.f, 0.f, 0.f, 0.f};
    int ra = ((mt - mt0) << 4) + (lane & 15);
    const char* ap = sA + (ra << 8);
    int sw = (ra & 7) << 4;
    short8_t av;
    av = *(const short8_t*)(ap + ((kb + 0) ^ sw));
    acc0 = __builtin_amdgcn_mfma_f32_16x16x32_bf16(av, bfA0, acc0, 0, 0, 0);
    acc1 = __builtin_amdgcn_mfma_f32_16x16x32_bf16(av, bfB0, acc1, 0, 0, 0);
    av = *(const short8_t*)(ap + ((kb + 64) ^ sw));
    acc0 = __builtin_amdgcn_mfma_f32_16x16x32_bf16(av, bfA1, acc0, 0, 0, 0);
    acc1 = __builtin_amdgcn_mfma_f32_16x16x32_bf16(av, bfB1, acc1, 0, 0, 0);
    av = *(const short8_t*)(ap + ((kb + 128) ^ sw));
    acc0 = __builtin_amdgcn_mfma_f32_16x16x32_bf16(av, bfA2, acc0, 0, 0, 0);
    acc1 = __builtin_amdgcn_mfma_f32_16x16x32_bf16(av, bfB2, acc1, 0, 0, 0);
    av = *(const short8_t*)(ap + ((kb + 192) ^ sw));
    acc0 = __builtin_amdgcn_mfma_f32_16x16x32_bf16(av, bfA3, acc0, 0, 0, 0);
    acc1 = __builtin_amdgcn_mfma_f32_16x16x32_bf16(av, bfB3, acc1, 0, 0, 0);
#pragma unroll
    for (int r = 0; r < 4; ++r) {
      int j = (mt << 4) + ((lane >> 4) << 2) + r;
      bool valid = (j < N_);
      float mj = valid ? mask[b * N_ + j] : 0.f;
      float sqm = mask_i * mj;
      float vj0 = valid ? VxeB[(size_t)j * H_ + colA] : 0.f;
      float vj1 = valid ? VxeB[(size_t)j * H_ + colB] : 0.f;
      float t0 = acc0[r] + add0 + vj0;
      float t1 = acc1[r] + add1 + vj1;
      if (valid) {
        size_t o = ((size_t)bi * N_ + j) * H_;
        ((unsigned short*)etmp)[o + colA] = f2b(t0);
        ((unsigned short*)etmp)[o + colB] = f2b(t1);
      }
      float g0 = sqm / (1.f + __expf(-t0));
      float g1 = sqm / (1.f + __expf(-t1));
      float vx0 = valid ? VxB[(size_t)j * H_ + colA] : 0.f;
      float vx1 = valid ? VxB[(size_t)j * H_ + colB] : 0.f;
      agg0 = fmaf(g0, vx0, agg0);
      agg1 = fmaf(g1, vx1, agg1);
      den0 += g0; den1 += g1;
      s1a = fmaf(t0, sqm, s1a);
      s1b = fmaf(t1, sqm, s1b);
      s2a = fmaf(t0 * sqm, t0, s2a);
      s2b = fmaf(t1 * sqm, t1, s2b);
    }
  }
#pragma unroll
  for (int d = 16; d <= 32; d <<= 1) {
    agg0 += __shfl_xor(agg0, d); agg1 += __shfl_xor(agg1, d);
    den0 += __shfl_xor(den0, d); den1 += __shfl_xor(den1, d);
    s1a += __shfl_xor(s1a, d);   s1b += __shfl_xor(s1b, d);
    s2a += __shfl_xor(s2a, d);   s2b += __shfl_xor(s2b, d);
  }
  if ((lane >> 4) == 0) {
    float* ps = pS + (size_t)blockIdx.x * 256;
    ps[colA] = s1a;
    ps[colB] = s1b;
    ps[128 + colA] = s2a;
    ps[128 + colB] = s2b;
    if (DO_X) {
      size_t po = ((size_t)jh * BN_ + bi) * H_;
      pAgg[po + colA] = agg0;
      pAgg[po + colB] = agg1;
      pDen[po + colA] = den0;
      pDen[po + colB] = den1;
    }
  }
}

// ---------------- xtmp finalize (sum jh partials) ----------------

__global__ __launch_bounds__(128) void k_xfin(
    const float* __restrict__ pAgg, const float* __restrict__ pDen,
    const float* __restrict__ Ux, float* __restrict__ xtmp) {
  int bi = blockIdx.x, h = threadIdx.x;
  float a0 = pAgg[(size_t)bi * H_ + h];
  float a1 = pAgg[((size_t)BN_ + bi) * H_ + h];
  float a2 = pAgg[((size_t)2 * BN_ + bi) * H_ + h];
  float a3 = pAgg[((size_t)3 * BN_ + bi) * H_ + h];
  float d0 = pDen[(size_t)bi * H_ + h];
  float d1 = pDen[((size_t)BN_ + bi) * H_ + h];
  float d2 = pDen[((size_t)2 * BN_ + bi) * H_ + h];
  float d3 = pDen[((size_t)3 * BN_ + bi) * H_ + h];
  float a = (a0 + a1) + (a2 + a3);
  float d = (d0 + d1) + (d2 + d3);
  xtmp[(size_t)bi * H_ + h] = Ux[(size_t)bi * H_ + h] + a / (1e-20f + d);
}

// ---------------- reduce partials -> sums (few atomics) ----------------
// blocks 0..31: BN-E (pS over 3200 blocks). blocks 32..63: BN-N (xtmp).

__global__ __launch_bounds__(256) void k_red(
    const float* __restrict__ pS, const float* __restrict__ xtmp,
    const float* __restrict__ mask, float* __restrict__ sums, int doN) {
  int g = blockIdx.x, t = threadIdx.x;
  if (g < 32) {
    float acc = 0.f;
    for (int blk = g * (NBLK_ / 32); blk < (g + 1) * (NBLK_ / 32); ++blk)
      acc += pS[(size_t)blk * 256 + t];
    atomicAdd(&sums[t], acc);
  } else if (doN) {
    int g2 = g - 32;
    int col = t & 127;
    bool sq = t >= 128;
    float acc = 0.f;
    for (int bi = g2 * (BN_ / 32); bi < (g2 + 1) * (BN_ / 32); ++bi) {
      float mi = mask[bi];
      float xt = xtmp[(size_t)bi * H_ + col];
      acc += (sq ? xt * xt : xt) * mi;
    }
    atomicAdd(&sums[256 + t], acc);
  }
}

// ---------------- head: A = e + relu(bnE(etmp)); y = relu(A@U+bU)@V + bV --

__global__ __launch_bounds__(256, 3) void k_head(
    const bf16* __restrict__ e, const bf16* __restrict__ etmp,
    const float* __restrict__ sumsPrev, const float* __restrict__ cnts,
    const float* __restrict__ gEp, const float* __restrict__ bEp,
    const bf16* __restrict__ UT, const float* __restrict__ Ub,
    const float* __restrict__ Vw, const float* __restrict__ Vb,
    const float* __restrict__ mask, float* __restrict__ y) {
  __shared__ __align__(16) char sA[MAXROWS_ * 256];
  __shared__ float part[4][MAXROWS_][2];
  __shared__ float ssE_s[256];
  const int bi = blockIdx.x >> 2;
  const int jh = blockIdx.x & 3;
  const int mt0 = (jh == 0) ? 0 : 3 * jh + 1;
  const int mt1 = 3 * jh + 4;
  const int b = bi / N_;
  const int t = threadIdx.x;
  const int lane = t & 63;
  const int w = t >> 6;
  const float mask_i = mask[bi];

  {
    int h = t & 127;
    float cntE = cnts[1];
    float mE = sumsPrev[h] / cntE;
    float vE = sumsPrev[128 + h] / cntE - mE * mE;
    float scE = gEp[h] * rsqrtf(vE + 1e-5f);
    ssE_s[t] = (t < 128) ? scE : (bEp[h] - mE * scE);
    __syncthreads();
  }

  const int colA = (w << 5) + (lane & 15);
  const int colB = colA + 16;
  const int kgrp = (lane >> 4) << 3;
  const short* wp0 = (const short*)UT + colA * H_ + kgrp;
  const short* wp1 = (const short*)UT + colB * H_ + kgrp;
  short8_t bfA0 = *(const short8_t*)(wp0);
  short8_t bfA1 = *(const short8_t*)(wp0 + 32);
  short8_t bfA2 = *(const short8_t*)(wp0 + 64);
  short8_t bfA3 = *(const short8_t*)(wp0 + 96);
  short8_t bfB0 = *(const short8_t*)(wp1);
  short8_t bfB1 = *(const short8_t*)(wp1 + 32);
  short8_t bfB2 = *(const short8_t*)(wp1 + 64);
  short8_t bfB3 = *(const short8_t*)(wp1 + 96);

  {
    const int nrt = (mt1 - mt0) << 4;
    const unsigned short* eb = (const unsigned short*)e + (size_t)bi * N_ * H_;
    const unsigned short* tb =
        (const unsigned short*)etmp + (size_t)bi * N_ * H_;
    for (int q4 = t; q4 < nrt * 32; q4 += 256) {
      int lr = q4 >> 5, k0 = (q4 & 31) << 2;
      int row = (mt0 << 4) + lr;
      float v0 = 0.f, v1 = 0.f, v2 = 0.f, v3 = 0.f;
      if (row < N_) {
        ushort4 e4 = *(const ushort4*)(eb + row * H_ + k0);
        ushort4 t4 = *(const ushort4*)(tb + row * H_ + k0);
        float mj = mask[b * N_ + row];
        bool msk = (mask_i * mj) > 0.f;
        float sc0 = ssE_s[k0 + 0], sc1 = ssE_s[k0 + 1];
        float sc2 = ssE_s[k0 + 2], sc3 = ssE_s[k0 + 3];
        float sh0 = ssE_s[128 + k0 + 0], sh1 = ssE_s[128 + k0 + 1];
        float sh2 = ssE_s[128 + k0 + 2], sh3 = ssE_s[128 + k0 + 3];
        float f0 = b2f16(t4.x), f1 = b2f16(t4.y);
        float f2 = b2f16(t4.z), f3 = b2f16(t4.w);
        v0 = b2f16(e4.x) + fmaxf(msk ? fmaf(f0, sc0, sh0) : f0, 0.f);
        v1 = b2f16(e4.y) + fmaxf(msk ? fmaf(f1, sc1, sh1) : f1, 0.f);
        v2 = b2f16(e4.z) + fmaxf(msk ? fmaf(f2, sc2, sh2) : f2, 0.f);
        v3 = b2f16(e4.w) + fmaxf(msk ? fmaf(f3, sc3, sh3) : f3, 0.f);
      }
      unsigned int p0 = ((unsigned int)f2b(v1) << 16) | f2b(v0);
      unsigned int p1 = ((unsigned int)f2b(v3) << 16) | f2b(v2);
      unsigned long long pk = ((unsigned long long)p1 << 32) | p0;
      int byo = (lr << 8) + ((k0 * 2) ^ ((lr & 7) << 4));
      *(unsigned long long*)(sA + byo) = pk;
    }
  }
  __syncthreads();

  float bu0 = Ub[colA], bu1 = Ub[colB];
  float v00 = Vw[colA * 2], v01 = Vw[colA * 2 + 1];
  float v10 = Vw[colB * 2], v11 = Vw[colB * 2 + 1];
  const int kb = (lane >> 4) << 4;

  for (int mt = mt0; mt < mt1; ++mt) {
    f32x4 acc0 = {0.f, 0.f, 0.f, 0.f}, acc1 = {0.f, 0.f, 0.f, 0.f};
    int ra = ((mt - mt0) << 4) + (lane & 15);
    const char* ap = sA + (ra << 8);
    int sw = (ra & 7) << 4;
    short8_t av;
    av = *(const short8_t*)(ap + ((kb + 0) ^ sw));
    acc0 = __builtin_amdgcn_mfma_f32_16x16x32_bf16(av, bfA0, acc0, 0, 0, 0);
    acc1 = __builtin_amdgcn_mfma_f32_16x16x32_bf16(av, bfB0, acc1, 0, 0, 0);
    av = *(const short8_t*)(ap + ((kb + 64) ^ sw));
    acc0 = __builtin_amdgcn_mfma_f32_16x16x32_bf16(av, bfA1, acc0, 0, 0, 0);
    acc1 = __builtin_amdgcn_mfma_f32_16x16x32_bf16(av, bfB1, acc1, 0, 0, 0);
    av = *(const short8_t*)(ap + ((kb + 128) ^ sw));
    acc0 = __builtin_amdgcn_mfma_f32_16x16x32_bf16(av, bfA2, acc0, 0, 0, 0);
    acc1 = __builtin_amdgcn_mfma_f32_16x16x32_bf16(av, bfB2, acc1, 0, 0, 0);
    av = *(const short8_t*)(ap + ((kb + 192) ^ sw));
    acc0 = __builtin_amdgcn_mfma_f32_16x16x32_bf16(av, bfA3, acc0, 0, 0, 0);
    acc1 = __builtin_amdgcn_mfma_f32_16x16x32_bf16(av, bfB3, acc1, 0, 0, 0);
#pragma unroll
    for (int r = 0; r < 4; ++r) {
      float h0v = fmaxf(acc0[r] + bu0, 0.f);
      float h1v = fmaxf(acc1[r] + bu1, 0.f);
      float p0 = h0v * v00 + h1v * v10;
      float p1 = h0v * v01 + h1v * v11;
#pragma unroll
      for (int d = 1; d < 16; d <<= 1) {
        p0 += __shfl_xor(p0, d);
        p1 += __shfl_xor(p1, d);
      }
      int jl = ((mt - mt0) << 4) + ((lane >> 4) << 2) + r;
      if ((lane & 15) == 0) { part[w][jl][0] = p0; part[w][jl][1] = p1; }
    }
  }
  __syncthreads();
  float vb0 = Vb[0], vb1 = Vb[1];
  const int nrt = (mt1 - mt0) << 4;
  for (int q = t; q < nrt * 2; q += 256) {
    int jl = q >> 1, c = q & 1;
    int j = (mt0 << 4) + jl;
    if (j < N_) {
      float s = part[0][jl][c] + part[1][jl][c] + part[2][jl][c] +
                part[3][jl][c] + (c ? vb1 : vb0);
      y[((size_t)bi * N_ + j) * 2 + c] = s;
    }
  }
}

// ---------------- launch ----------------

extern "C" void kernel_launch(void* const* d_in, const int* in_sizes, int n_in,
                              void* d_out, int out_size, void* d_ws,
                              size_t ws_size, hipStream_t stream) {
  const int*   x_edges = (const int*)d_in[0];
  const float* ev      = (const float*)d_in[1];
  const float* coord   = (const float*)d_in[2];
  const float* mask    = (const float*)d_in[3];
  const float* w_coord = (const float*)d_in[4];
  const float* w_eval  = (const float*)d_in[5];
  const float* emb     = (const float*)d_in[6];
  const float* eUw = (const float*)d_in[7];
  const float* eUb = (const float*)d_in[8];
  const float* eVw = (const float*)d_in[9];
  const float* eVb = (const float*)d_in[10];
  const float* nUw = (const float*)d_in[11];
  const float* nUb = (const float*)d_in[12];
  const float* nVw = (const float*)d_in[13];
  const float* nVb = (const float*)d_in[14];
  const float* gE  = (const float*)d_in[15];
  const float* bE  = (const float*)d_in[16];
  const float* gN  = (const float*)d_in[17];
  const float* bN  = (const float*)d_in[18];
  const float* mUw = (const float*)d_in[19];
  const float* mUb = (const float*)d_in[20];
  const float* mVw = (const float*)d_in[21];
  const float* mVb = (const float*)d_in[22];

  char* ws = (char*)d_ws;
  size_t off = 0;
  auto alloc = [&](size_t bytes) {
    void* p = ws + off;
    off += (bytes + 255) & ~(size_t)255;
    return p;
  };
  bf16* e     = (bf16*)alloc((size_t)B_ * N_ * N_ * H_ * 2);   // 40.96 MB
  bf16* etmp  = (bf16*)alloc((size_t)B_ * N_ * N_ * H_ * 2);   // 40.96 MB
  float* x    = (float*)alloc((size_t)BN_ * H_ * 4);
  float* Vxe  = (float*)alloc((size_t)BN_ * H_ * 4);
  float* Ux   = (float*)alloc((size_t)BN_ * H_ * 4);
  float* Vx   = (float*)alloc((size_t)BN_ * H_ * 4);
  float* xtmp = (float*)alloc((size_t)BN_ * H_ * 4);
  float* pS   = (float*)alloc((size_t)NBLK_ * 256 * 4);        // 3.28 MB
  float* pAgg = (float*)alloc((size_t)JT_ * BN_ * H_ * 4);     // 1.64 MB
  float* pDen = (float*)alloc((size_t)JT_ * BN_ * H_ * 4);     // 1.64 MB
  float* sums = (float*)alloc(3 * 512 * 4);  // 3 layers x [s1E,s2E,s1N,s2N]
  float* cnts = (float*)alloc(256);
  bf16* WT    = (bf16*)alloc((size_t)4 * H_ * H_ * 2);

  hipMemsetAsync(sums, 0, 3 * 512 * 4, stream);
  k_pre<<<405, 256, 0, stream>>>(coord, w_coord, eUw, mUw, mask, x, WT, cnts);

  float* sums0 = sums;
  float* sums1 = sums + 512;
  float* sums2 = sums + 1024;

  // layer 0
  k_node_lin<0><<<BN_, 128, 0, stream>>>(
      x, xtmp, sums0, cnts, gN, bN, eVw, eVb, nUw, nUb, nVw, nVb, mask, Vxe,
      Ux, Vx);
  k_edge<0, true><<<NBLK_, 256, 0, stream>>>(
      e, etmp, sums0, cnts, gE, bE, x_edges, ev, w_eval, emb, WT, eUb, Vxe,
      Vx, mask, pS, pAgg, pDen);
  k_xfin<<<BN_, 128, 0, stream>>>(pAgg, pDen, Ux, xtmp);
  k_red<<<64, 256, 0, stream>>>(pS, xtmp, mask, sums0, 1);
  // layer 1
  k_node_lin<1><<<BN_, 128, 0, stream>>>(
      x, xtmp, sums0, cnts, gN, bN, eVw + H_ * H_, eVb + H_, nUw + H_ * H_,
      nUb + H_, nVw + H_ * H_, nVb + H_, mask, Vxe, Ux, Vx);
  k_edge<2, true><<<NBLK_, 256, 0, stream>>>(
      e, etmp, sums0, cnts, gE, bE, x_edges, ev, w_eval, emb, WT + H_ * H_,
      eUb + H_, Vxe, Vx, mask, pS, pAgg, pDen);
  k_xfin<<<BN_, 128, 0, stream>>>(pAgg, pDen, Ux, xtmp);
  k_red<<<64, 256, 0, stream>>>(pS, xtmp, mask, sums1, 1);
  // layer 2
  k_node_lin<1><<<BN_, 128, 0, stream>>>(
      x, xtmp, sums1, cnts, gN + H_, bN + H_, eVw + 2 * H_ * H_,
      eVb + 2 * H_, nUw + 2 * H_ * H_, nUb + 2 * H_, nVw + 2 * H_ * H_,
      nVb + 2 * H_, mask, Vxe, Ux, Vx);
  k_edge<1, false><<<NBLK_, 256, 0, stream>>>(
      e, etmp, sums1, cnts, gE + H_, bE + H_, x_edges, ev, w_eval, emb,
      WT + 2 * H_ * H_, eUb + 2 * H_, Vxe, Vx, mask, pS, pAgg, pDen);
  k_red<<<64, 256, 0, stream>>>(pS, xtmp, mask, sums2, 0);
  // head
  k_head<<<NBLK_, 256, 0, stream>>>(e, etmp, sums2, cnts, gE + 2 * H_,
                                    bE + 2 * H_, WT + (size_t)3 * H_ * H_,
                                    mUb, mVw, mVb, mask, (float*)d_out);
}

// Round 14
// 340.835 us; speedup vs baseline: 1.1134x; 1.0052x over previous
//
#include <hip/hip_runtime.h>
#include <hip/hip_bf16.h>

// ConvTSP gated-GCN forward, MI355X (gfx950). Round 14.
// B=4, N=200, H=128, L=3. f32 in/out, x_edges int32.
//
// R13 (342.6us) = validated optimum for hot kernels; every perturbation
// (R10 (256,6), R11 (256,4)+rcpf, R12 fused atomics) regressed. R14 keeps
// k_edge/k_head/k_node_lin BYTE-IDENTICAL and only cuts the serial
// small-kernel chain (was ~78us over 9 dispatches):
//  - k_xfin folded into k_red's doN blocks (same 64-block/32-adds-per-
//    address atomic pattern as R13 -- NOT R12's 800x contention).
//  - x0 computed inline in k_node_lin<0> (row-local); k_pre -> 5 blocks.
// Dispatches 14 -> 12.

typedef __hip_bfloat16 bf16;
typedef __attribute__((ext_vector_type(8))) short short8_t;
typedef __attribute__((ext_vector_type(4))) float f32x4;

#define B_ 4
#define N_ 200
#define H_ 128
#define BN_ (B_ * N_)
#define JT_ 4
#define NBLK_ (BN_ * JT_)
#define MAXROWS_ 64

__device__ __forceinline__ unsigned short f2b(float f) {
  unsigned int i = __float_as_uint(f);
  i = (i + 0x7fffu + ((i >> 16) & 1u)) >> 16;  // RNE
  return (unsigned short)i;
}
__device__ __forceinline__ float b2f16(unsigned short u) {
  return __uint_as_float((unsigned int)u << 16);
}

// ---------------- fused prelude: prep_w | cnt (5 blocks) ----------------

__global__ __launch_bounds__(256) void k_pre(
    const float* __restrict__ eUw, const float* __restrict__ mUw,
    const float* __restrict__ mask, bf16* __restrict__ WT,
    float* __restrict__ cnts) {
  int blk = blockIdx.x, t = threadIdx.x;
  if (blk < 4) {
    const float* src = (blk < 3) ? (eUw + (size_t)blk * H_ * H_) : mUw;
    bf16* dst = WT + (size_t)blk * H_ * H_;
    for (int q = t; q < H_ * H_; q += 256) {
      int out = q >> 7, in = q & 127;
      dst[q] = __float2bfloat16(src[in * H_ + out]);
    }
  } else {
    int b = t >> 6, l = t & 63;
    float s = 0.f;
    for (int n = l; n < N_; n += 64) s += mask[b * N_ + n];
#pragma unroll
    for (int d = 1; d < 64; d <<= 1) s += __shfl_xor(s, d);
    __shared__ float ms[B_];
    if (l == 0) ms[b] = s;
    __syncthreads();
    if (t == 0) {
      float cn = 0.f, ce = 0.f;
      for (int k = 0; k < B_; ++k) { cn += ms[k]; ce += ms[k] * ms[k]; }
      cnts[0] = cn; cnts[1] = ce;
    }
  }
}

// ---------------- node linears (+fused x init/update, inline ssN) --------

template <int UPD>
__global__ __launch_bounds__(128) void k_node_lin(
    float* __restrict__ x, const float* __restrict__ coord,
    const float* __restrict__ w_coord, const float* __restrict__ xtmp,
    const float* __restrict__ sumsPrev, const float* __restrict__ cnts,
    const float* __restrict__ gNp, const float* __restrict__ bNp,
    const float* __restrict__ eVw, const float* __restrict__ eVb,
    const float* __restrict__ nUw, const float* __restrict__ nUb,
    const float* __restrict__ nVw, const float* __restrict__ nVb,
    const float* __restrict__ mask, float* __restrict__ Vxe,
    float* __restrict__ Ux, float* __restrict__ Vx) {
  __shared__ float xr[H_];
  int bi = blockIdx.x, h = threadIdx.x;
  float m = mask[bi];
  float xv;
  if (UPD) {
    xv = x[(size_t)bi * H_ + h];
    float cntN = cnts[0];
    float mN = sumsPrev[256 + h] / cntN;
    float vN = sumsPrev[384 + h] / cntN - mN * mN;
    float scN = gNp[h] * rsqrtf(vN + 1e-5f);
    float shN = bNp[h] - mN * scN;
    float tv = xtmp[(size_t)bi * H_ + h];
    float xn = (m > 0.f) ? fmaf(tv, scN, shN) : tv;
    xv += fmaxf(xn, 0.f);
  } else {
    float c0 = coord[bi * 2 + 0], c1 = coord[bi * 2 + 1];
    xv = c0 * w_coord[h] + c1 * w_coord[H_ + h];
  }
  x[(size_t)bi * H_ + h] = xv;
  xr[h] = xv;
  __syncthreads();
  float a = 0.f, bvv = 0.f, c = 0.f;
#pragma unroll 4
  for (int k = 0; k < H_; ++k) {
    float kx = xr[k];
    a   = fmaf(kx, eVw[k * H_ + h], a);
    bvv = fmaf(kx, nUw[k * H_ + h], bvv);
    c   = fmaf(kx, nVw[k * H_ + h], c);
  }
  Vxe[(size_t)bi * H_ + h] = m * (a + eVb[h]);
  Ux[(size_t)bi * H_ + h]  = m * (bvv + nUb[h]);
  Vx[(size_t)bi * H_ + h]  = m * (c + nVb[h]);
}

// ---------------- big kernel: staged-update + GEMM + epilogue ------------
// grid = BN_*JT_. blockIdx -> (bi, jh). Block owns j-tiles [mt0,mt1).
// MODE 0: layer 0. A = e0 from raw inputs. No e write.
// MODE 2: layer 1. A = e0(recomputed) + relu(bnE(etmp)). Writes e (bf16).
// MODE 1: layer 2. A = e + relu(bnE(etmp)); e updated in place.
// NO global atomics: per-block partials to pS / pAgg / pDen.

template <int MODE, bool DO_X>
__global__ __launch_bounds__(256, 3) void k_edge(
    bf16* __restrict__ e, bf16* __restrict__ etmp,
    const float* __restrict__ sumsPrev, const float* __restrict__ cnts,
    const float* __restrict__ gEp, const float* __restrict__ bEp,
    const int* __restrict__ xe, const float* __restrict__ ev,
    const float* __restrict__ w_eval, const float* __restrict__ emb,
    const bf16* __restrict__ WT, const float* __restrict__ eUb,
    const float* __restrict__ Vxe, const float* __restrict__ Vx,
    const float* __restrict__ mask, float* __restrict__ pS,
    float* __restrict__ pAgg, float* __restrict__ pDen) {
  __shared__ __align__(16) char sA[MAXROWS_ * 256];
  __shared__ float ssE_s[256];
  const int bi = blockIdx.x >> 2;
  const int jh = blockIdx.x & 3;
  const int mt0 = (jh == 0) ? 0 : 3 * jh + 1;
  const int mt1 = 3 * jh + 4;
  const int b = bi / N_;
  const int t = threadIdx.x;
  const int lane = t & 63;
  const int w = t >> 6;
  const float mask_i = mask[bi];

  // inline ssE from previous layer's sums (L2-hot, 2KB)
  if (MODE != 0) {
    int h = t & 127;
    float cntE = cnts[1];
    float mE = sumsPrev[h] / cntE;
    float vE = sumsPrev[128 + h] / cntE - mE * mE;
    float scE = gEp[h] * rsqrtf(vE + 1e-5f);
    ssE_s[t] = (t < 128) ? scE : (bEp[h] - mE * scE);
    __syncthreads();
  }

  // --- B fragments: named, no arrays ---
  const int colA = (w << 5) + (lane & 15);
  const int colB = colA + 16;
  const int kgrp = (lane >> 4) << 3;
  const short* wp0 = (const short*)WT + colA * H_ + kgrp;
  const short* wp1 = (const short*)WT + colB * H_ + kgrp;
  short8_t bfA0 = *(const short8_t*)(wp0);
  short8_t bfA1 = *(const short8_t*)(wp0 + 32);
  short8_t bfA2 = *(const short8_t*)(wp0 + 64);
  short8_t bfA3 = *(const short8_t*)(wp0 + 96);
  short8_t bfB0 = *(const short8_t*)(wp1);
  short8_t bfB1 = *(const short8_t*)(wp1 + 32);
  short8_t bfB2 = *(const short8_t*)(wp1 + 64);
  short8_t bfB3 = *(const short8_t*)(wp1 + 96);

  // --- staging: rows [mt0*16, mt1*16), 8B granule, named scalars ---
  {
    const int nrt = (mt1 - mt0) << 4;  // 48 or 64 rows
    unsigned short* eb = (unsigned short*)e + (size_t)bi * N_ * H_;
    const unsigned short* tb =
        (const unsigned short*)etmp + (size_t)bi * N_ * H_;
    for (int q4 = t; q4 < nrt * 32; q4 += 256) {
      int lr = q4 >> 5, k0 = (q4 & 31) << 2;
      int row = (mt0 << 4) + lr;
      float v0 = 0.f, v1 = 0.f, v2 = 0.f, v3 = 0.f;
      if (row < N_) {
        if (MODE == 0 || MODE == 2) {
          if (k0 < 64) {
            float evv = ev[bi * N_ + row];
            float4 we = *(const float4*)(w_eval + k0);
            v0 = evv * we.x; v1 = evv * we.y;
            v2 = evv * we.z; v3 = evv * we.w;
          } else {
            float4 em4 = *(const float4*)(emb + xe[bi * N_ + row] * 64 + (k0 - 64));
            v0 = em4.x; v1 = em4.y; v2 = em4.z; v3 = em4.w;
          }
        } else {
          ushort4 e4 = *(const ushort4*)(eb + row * H_ + k0);
          v0 = b2f16(e4.x); v1 = b2f16(e4.y);
          v2 = b2f16(e4.z); v3 = b2f16(e4.w);
        }
        if (MODE != 0) {
          ushort4 t4 = *(const ushort4*)(tb + row * H_ + k0);
          float mj = mask[b * N_ + row];
          bool msk = (mask_i * mj) > 0.f;
          float sc0 = ssE_s[k0 + 0], sc1 = ssE_s[k0 + 1];
          float sc2 = ssE_s[k0 + 2], sc3 = ssE_s[k0 + 3];
          float sh0 = ssE_s[128 + k0 + 0], sh1 = ssE_s[128 + k0 + 1];
          float sh2 = ssE_s[128 + k0 + 2], sh3 = ssE_s[128 + k0 + 3];
          float f0 = b2f16(t4.x), f1 = b2f16(t4.y);
          float f2 = b2f16(t4.z), f3 = b2f16(t4.w);
          v0 += fmaxf(msk ? fmaf(f0, sc0, sh0) : f0, 0.f);
          v1 += fmaxf(msk ? fmaf(f1, sc1, sh1) : f1, 0.f);
          v2 += fmaxf(msk ? fmaf(f2, sc2, sh2) : f2, 0.f);
          v3 += fmaxf(msk ? fmaf(f3, sc3, sh3) : f3, 0.f);
        }
      }
      unsigned int p0 = ((unsigned int)f2b(v1) << 16) | f2b(v0);
      unsigned int p1 = ((unsigned int)f2b(v3) << 16) | f2b(v2);
      if (MODE != 0 && row < N_)
        *(uint2*)(eb + row * H_ + k0) = make_uint2(p0, p1);  // persist e_l
      unsigned long long pk = ((unsigned long long)p1 << 32) | p0;
      int byo = (lr << 8) + ((k0 * 2) ^ ((lr & 7) << 4));
      *(unsigned long long*)(sA + byo) = pk;
    }
  }
  __syncthreads();

  // --- GEMM + gate/agg/BN epilogue (R8 shape, no arrays) ---
  const float add0 = eUb[colA] + Vxe[(size_t)bi * H_ + colA];
  const float add1 = eUb[colB] + Vxe[(size_t)bi * H_ + colB];
  const float* VxeB = Vxe + (size_t)b * N_ * H_;
  const float* VxB  = Vx  + (size_t)b * N_ * H_;

  float agg0 = 0.f, agg1 = 0.f, den0 = 0.f, den1 = 0.f;
  float s1a = 0.f, s1b = 0.f, s2a = 0.f, s2b = 0.f;
  const int kb = (lane >> 4) << 4;

  for (int mt = mt0; mt < mt1; ++mt) {
    f32x4 acc0 = {0.f, 0.f, 0.f, 0.f}, acc1 = {0.f, 0.f, 0.f, 0.f};
    int ra = ((mt - mt0) << 4) + (lane & 15);
    const char* ap = sA + (ra << 8);
    int sw = (ra & 7) << 4;
    short8_t av;
    av = *(const short8_t*)(ap + ((kb + 0) ^ sw));
    acc0 = __builtin_amdgcn_mfma_f32_16x16x32_bf16(av, bfA0, acc0, 0, 0, 0);
    acc1 = __builtin_amdgcn_mfma_f32_16x16x32_bf16(av, bfB0, acc1, 0, 0, 0);
    av = *(const short8_t*)(ap + ((kb + 64) ^ sw));
    acc0 = __builtin_amdgcn_mfma_f32_16x16x32_bf16(av, bfA1, acc0, 0, 0, 0);
    acc1 = __builtin_amdgcn_mfma_f32_16x16x32_bf16(av, bfB1, acc1, 0, 0, 0);
    av = *(const short8_t*)(ap + ((kb + 128) ^ sw));
    acc0 = __builtin_amdgcn_mfma_f32_16x16x32_bf16(av, bfA2, acc0, 0, 0, 0);
    acc1 = __builtin_amdgcn_mfma_f32_16x16x32_bf16(av, bfB2, acc1, 0, 0, 0);
    av = *(const short8_t*)(ap + ((kb + 192) ^ sw));
    acc0 = __builtin_amdgcn_mfma_f32_16x16x32_bf16(av, bfA3, acc0, 0, 0, 0);
    acc1 = __builtin_amdgcn_mfma_f32_16x16x32_bf16(av, bfB3, acc1, 0, 0, 0);
#pragma unroll
    for (int r = 0; r < 4; ++r) {
      int j = (mt << 4) + ((lane >> 4) << 2) + r;
      bool valid = (j < N_);
      float mj = valid ? mask[b * N_ + j] : 0.f;
      float sqm = mask_i * mj;
      float vj0 = valid ? VxeB[(size_t)j * H_ + colA] : 0.f;
      float vj1 = valid ? VxeB[(size_t)j * H_ + colB] : 0.f;
      float t0 = acc0[r] + add0 + vj0;
      float t1 = acc1[r] + add1 + vj1;
      if (valid) {
        size_t o = ((size_t)bi * N_ + j) * H_;
        ((unsigned short*)etmp)[o + colA] = f2b(t0);
        ((unsigned short*)etmp)[o + colB] = f2b(t1);
      }
      float g0 = sqm / (1.f + __expf(-t0));
      float g1 = sqm / (1.f + __expf(-t1));
      float vx0 = valid ? VxB[(size_t)j * H_ + colA] : 0.f;
      float vx1 = valid ? VxB[(size_t)j * H_ + colB] : 0.f;
      agg0 = fmaf(g0, vx0, agg0);
      agg1 = fmaf(g1, vx1, agg1);
      den0 += g0; den1 += g1;
      s1a = fmaf(t0, sqm, s1a);
      s1b = fmaf(t1, sqm, s1b);
      s2a = fmaf(t0 * sqm, t0, s2a);
      s2b = fmaf(t1 * sqm, t1, s2b);
    }
  }
#pragma unroll
  for (int d = 16; d <= 32; d <<= 1) {
    agg0 += __shfl_xor(agg0, d); agg1 += __shfl_xor(agg1, d);
    den0 += __shfl_xor(den0, d); den1 += __shfl_xor(den1, d);
    s1a += __shfl_xor(s1a, d);   s1b += __shfl_xor(s1b, d);
    s2a += __shfl_xor(s2a, d);   s2b += __shfl_xor(s2b, d);
  }
  if ((lane >> 4) == 0) {
    float* ps = pS + (size_t)blockIdx.x * 256;
    ps[colA] = s1a;
    ps[colB] = s1b;
    ps[128 + colA] = s2a;
    ps[128 + colB] = s2b;
    if (DO_X) {
      size_t po = ((size_t)jh * BN_ + bi) * H_;
      pAgg[po + colA] = agg0;
      pAgg[po + colB] = agg1;
      pDen[po + colA] = den0;
      pDen[po + colB] = den1;
    }
  }
}

// ---------------- reduce: pS -> BN-E sums; xtmp compute + BN-N sums ------
// blocks 0..31: BN-E (pS over 3200 blocks, 32 adds/address).
// blocks 32..63 (doN): per-bi xtmp from pAgg/pDen (contention-free write)
//                      + BN-N partial atomics (32 adds/address).

__global__ __launch_bounds__(256) void k_red(
    const float* __restrict__ pS, const float* __restrict__ pAgg,
    const float* __restrict__ pDen, const float* __restrict__ Ux,
    const float* __restrict__ mask, float* __restrict__ xtmp,
    float* __restrict__ sums, int doN) {
  int g = blockIdx.x, t = threadIdx.x;
  if (g < 32) {
    float acc = 0.f;
    for (int blk = g * (NBLK_ / 32); blk < (g + 1) * (NBLK_ / 32); ++blk)
      acc += pS[(size_t)blk * 256 + t];
    atomicAdd(&sums[t], acc);
  } else if (doN) {
    int g2 = g - 32;
    int col = t & 127;
    bool sq = t >= 128;
    float acc = 0.f;
    for (int bi = g2 * (BN_ / 32); bi < (g2 + 1) * (BN_ / 32); ++bi) {
      float a = pAgg[(size_t)bi * H_ + col] +
                pAgg[((size_t)BN_ + bi) * H_ + col] +
                pAgg[((size_t)2 * BN_ + bi) * H_ + col] +
                pAgg[((size_t)3 * BN_ + bi) * H_ + col];
      float d = pDen[(size_t)bi * H_ + col] +
                pDen[((size_t)BN_ + bi) * H_ + col] +
                pDen[((size_t)2 * BN_ + bi) * H_ + col] +
                pDen[((size_t)3 * BN_ + bi) * H_ + col];
      float xt = Ux[(size_t)bi * H_ + col] + a / (1e-20f + d);
      if (!sq) xtmp[(size_t)bi * H_ + col] = xt;
      float mi = mask[bi];
      acc += (sq ? xt * xt : xt) * mi;
    }
    atomicAdd(&sums[256 + t], acc);
  }
}

// ---------------- head: A = e + relu(bnE(etmp)); y = relu(A@U+bU)@V + bV --

__global__ __launch_bounds__(256, 3) void k_head(
    const bf16* __restrict__ e, const bf16* __restrict__ etmp,
    const float* __restrict__ sumsPrev, const float* __restrict__ cnts,
    const float* __restrict__ gEp, const float* __restrict__ bEp,
    const bf16* __restrict__ UT, const float* __restrict__ Ub,
    const float* __restrict__ Vw, const float* __restrict__ Vb,
    const float* __restrict__ mask, float* __restrict__ y) {
  __shared__ __align__(16) char sA[MAXROWS_ * 256];
  __shared__ float part[4][MAXROWS_][2];
  __shared__ float ssE_s[256];
  const int bi = blockIdx.x >> 2;
  const int jh = blockIdx.x & 3;
  const int mt0 = (jh == 0) ? 0 : 3 * jh + 1;
  const int mt1 = 3 * jh + 4;
  const int b = bi / N_;
  const int t = threadIdx.x;
  const int lane = t & 63;
  const int w = t >> 6;
  const float mask_i = mask[bi];

  {
    int h = t & 127;
    float cntE = cnts[1];
    float mE = sumsPrev[h] / cntE;
    float vE = sumsPrev[128 + h] / cntE - mE * mE;
    float scE = gEp[h] * rsqrtf(vE + 1e-5f);
    ssE_s[t] = (t < 128) ? scE : (bEp[h] - mE * scE);
    __syncthreads();
  }

  const int colA = (w << 5) + (lane & 15);
  const int colB = colA + 16;
  const int kgrp = (lane >> 4) << 3;
  const short* wp0 = (const short*)UT + colA * H_ + kgrp;
  const short* wp1 = (const short*)UT + colB * H_ + kgrp;
  short8_t bfA0 = *(const short8_t*)(wp0);
  short8_t bfA1 = *(const short8_t*)(wp0 + 32);
  short8_t bfA2 = *(const short8_t*)(wp0 + 64);
  short8_t bfA3 = *(const short8_t*)(wp0 + 96);
  short8_t bfB0 = *(const short8_t*)(wp1);
  short8_t bfB1 = *(const short8_t*)(wp1 + 32);
  short8_t bfB2 = *(const short8_t*)(wp1 + 64);
  short8_t bfB3 = *(const short8_t*)(wp1 + 96);

  {
    const int nrt = (mt1 - mt0) << 4;
    const unsigned short* eb = (const unsigned short*)e + (size_t)bi * N_ * H_;
    const unsigned short* tb =
        (const unsigned short*)etmp + (size_t)bi * N_ * H_;
    for (int q4 = t; q4 < nrt * 32; q4 += 256) {
      int lr = q4 >> 5, k0 = (q4 & 31) << 2;
      int row = (mt0 << 4) + lr;
      float v0 = 0.f, v1 = 0.f, v2 = 0.f, v3 = 0.f;
      if (row < N_) {
        ushort4 e4 = *(const ushort4*)(eb + row * H_ + k0);
        ushort4 t4 = *(const ushort4*)(tb + row * H_ + k0);
        float mj = mask[b * N_ + row];
        bool msk = (mask_i * mj) > 0.f;
        float sc0 = ssE_s[k0 + 0], sc1 = ssE_s[k0 + 1];
        float sc2 = ssE_s[k0 + 2], sc3 = ssE_s[k0 + 3];
        float sh0 = ssE_s[128 + k0 + 0], sh1 = ssE_s[128 + k0 + 1];
        float sh2 = ssE_s[128 + k0 + 2], sh3 = ssE_s[128 + k0 + 3];
        float f0 = b2f16(t4.x), f1 = b2f16(t4.y);
        float f2 = b2f16(t4.z), f3 = b2f16(t4.w);
        v0 = b2f16(e4.x) + fmaxf(msk ? fmaf(f0, sc0, sh0) : f0, 0.f);
        v1 = b2f16(e4.y) + fmaxf(msk ? fmaf(f1, sc1, sh1) : f1, 0.f);
        v2 = b2f16(e4.z) + fmaxf(msk ? fmaf(f2, sc2, sh2) : f2, 0.f);
        v3 = b2f16(e4.w) + fmaxf(msk ? fmaf(f3, sc3, sh3) : f3, 0.f);
      }
      unsigned int p0 = ((unsigned int)f2b(v1) << 16) | f2b(v0);
      unsigned int p1 = ((unsigned int)f2b(v3) << 16) | f2b(v2);
      unsigned long long pk = ((unsigned long long)p1 << 32) | p0;
      int byo = (lr << 8) + ((k0 * 2) ^ ((lr & 7) << 4));
      *(unsigned long long*)(sA + byo) = pk;
    }
  }
  __syncthreads();

  float bu0 = Ub[colA], bu1 = Ub[colB];
  float v00 = Vw[colA * 2], v01 = Vw[colA * 2 + 1];
  float v10 = Vw[colB * 2], v11 = Vw[colB * 2 + 1];
  const int kb = (lane >> 4) << 4;

  for (int mt = mt0; mt < mt1; ++mt) {
    f32x4 acc0 = {0.f, 0.f, 0.f, 0.f}, acc1 = {0.f, 0.f, 0.f, 0.f};
    int ra = ((mt - mt0) << 4) + (lane & 15);
    const char* ap = sA + (ra << 8);
    int sw = (ra & 7) << 4;
    short8_t av;
    av = *(const short8_t*)(ap + ((kb + 0) ^ sw));
    acc0 = __builtin_amdgcn_mfma_f32_16x16x32_bf16(av, bfA0, acc0, 0, 0, 0);
    acc1 = __builtin_amdgcn_mfma_f32_16x16x32_bf16(av, bfB0, acc1, 0, 0, 0);
    av = *(const short8_t*)(ap + ((kb + 64) ^ sw));
    acc0 = __builtin_amdgcn_mfma_f32_16x16x32_bf16(av, bfA1, acc0, 0, 0, 0);
    acc1 = __builtin_amdgcn_mfma_f32_16x16x32_bf16(av, bfB1, acc1, 0, 0, 0);
    av = *(const short8_t*)(ap + ((kb + 128) ^ sw));
    acc0 = __builtin_amdgcn_mfma_f32_16x16x32_bf16(av, bfA2, acc0, 0, 0, 0);
    acc1 = __builtin_amdgcn_mfma_f32_16x16x32_bf16(av, bfB2, acc1, 0, 0, 0);
    av = *(const short8_t*)(ap + ((kb + 192) ^ sw));
    acc0 = __builtin_amdgcn_mfma_f32_16x16x32_bf16(av, bfA3, acc0, 0, 0, 0);
    acc1 = __builtin_amdgcn_mfma_f32_16x16x32_bf16(av, bfB3, acc1, 0, 0, 0);
#pragma unroll
    for (int r = 0; r < 4; ++r) {
      float h0v = fmaxf(acc0[r] + bu0, 0.f);
      float h1v = fmaxf(acc1[r] + bu1, 0.f);
      float p0 = h0v * v00 + h1v * v10;
      float p1 = h0v * v01 + h1v * v11;
#pragma unroll
      for (int d = 1; d < 16; d <<= 1) {
        p0 += __shfl_xor(p0, d);
        p1 += __shfl_xor(p1, d);
      }
      int jl = ((mt - mt0) << 4) + ((lane >> 4) << 2) + r;
      if ((lane & 15) == 0) { part[w][jl][0] = p0; part[w][jl][1] = p1; }
    }
  }
  __syncthreads();
  float vb0 = Vb[0], vb1 = Vb[1];
  const int nrt = (mt1 - mt0) << 4;
  for (int q = t; q < nrt * 2; q += 256) {
    int jl = q >> 1, c = q & 1;
    int j = (mt0 << 4) + jl;
    if (j < N_) {
      float s = part[0][jl][c] + part[1][jl][c] + part[2][jl][c] +
                part[3][jl][c] + (c ? vb1 : vb0);
      y[((size_t)bi * N_ + j) * 2 + c] = s;
    }
  }
}

// ---------------- launch ----------------

extern "C" void kernel_launch(void* const* d_in, const int* in_sizes, int n_in,
                              void* d_out, int out_size, void* d_ws,
                              size_t ws_size, hipStream_t stream) {
  const int*   x_edges = (const int*)d_in[0];
  const float* ev      = (const float*)d_in[1];
  const float* coord   = (const float*)d_in[2];
  const float* mask    = (const float*)d_in[3];
  const float* w_coord = (const float*)d_in[4];
  const float* w_eval  = (const float*)d_in[5];
  const float* emb     = (const float*)d_in[6];
  const float* eUw = (const float*)d_in[7];
  const float* eUb = (const float*)d_in[8];
  const float* eVw = (const float*)d_in[9];
  const float* eVb = (const float*)d_in[10];
  const float* nUw = (const float*)d_in[11];
  const float* nUb = (const float*)d_in[12];
  const float* nVw = (const float*)d_in[13];
  const float* nVb = (const float*)d_in[14];
  const float* gE  = (const float*)d_in[15];
  const float* bE  = (const float*)d_in[16];
  const float* gN  = (const float*)d_in[17];
  const float* bN  = (const float*)d_in[18];
  const float* mUw = (const float*)d_in[19];
  const float* mUb = (const float*)d_in[20];
  const float* mVw = (const float*)d_in[21];
  const float* mVb = (const float*)d_in[22];

  char* ws = (char*)d_ws;
  size_t off = 0;
  auto alloc = [&](size_t bytes) {
    void* p = ws + off;
    off += (bytes + 255) & ~(size_t)255;
    return p;
  };
  bf16* e     = (bf16*)alloc((size_t)B_ * N_ * N_ * H_ * 2);   // 40.96 MB
  bf16* etmp  = (bf16*)alloc((size_t)B_ * N_ * N_ * H_ * 2);   // 40.96 MB
  float* x    = (float*)alloc((size_t)BN_ * H_ * 4);
  float* Vxe  = (float*)alloc((size_t)BN_ * H_ * 4);
  float* Ux   = (float*)alloc((size_t)BN_ * H_ * 4);
  float* Vx   = (float*)alloc((size_t)BN_ * H_ * 4);
  float* xtmp = (float*)alloc((size_t)BN_ * H_ * 4);
  float* pS   = (float*)alloc((size_t)NBLK_ * 256 * 4);        // 3.28 MB
  float* pAgg = (float*)alloc((size_t)JT_ * BN_ * H_ * 4);     // 1.64 MB
  float* pDen = (float*)alloc((size_t)JT_ * BN_ * H_ * 4);     // 1.64 MB
  float* sums = (float*)alloc(3 * 512 * 4);  // 3 layers x [s1E,s2E,s1N,s2N]
  float* cnts = (float*)alloc(256);
  bf16* WT    = (bf16*)alloc((size_t)4 * H_ * H_ * 2);

  hipMemsetAsync(sums, 0, 3 * 512 * 4, stream);
  k_pre<<<5, 256, 0, stream>>>(eUw, mUw, mask, WT, cnts);

  float* sums0 = sums;
  float* sums1 = sums + 512;
  float* sums2 = sums + 1024;

  // layer 0
  k_node_lin<0><<<BN_, 128, 0, stream>>>(
      x, coord, w_coord, xtmp, sums0, cnts, gN, bN, eVw, eVb, nUw, nUb, nVw,
      nVb, mask, Vxe, Ux, Vx);
  k_edge<0, true><<<NBLK_, 256, 0, stream>>>(
      e, etmp, sums0, cnts, gE, bE, x_edges, ev, w_eval, emb, WT, eUb, Vxe,
      Vx, mask, pS, pAgg, pDen);
  k_red<<<64, 256, 0, stream>>>(pS, pAgg, pDen, Ux, mask, xtmp, sums0, 1);
  // layer 1
  k_node_lin<1><<<BN_, 128, 0, stream>>>(
      x, coord, w_coord, xtmp, sums0, cnts, gN, bN, eVw + H_ * H_, eVb + H_,
      nUw + H_ * H_, nUb + H_, nVw + H_ * H_, nVb + H_, mask, Vxe, Ux, Vx);
  k_edge<2, true><<<NBLK_, 256, 0, stream>>>(
      e, etmp, sums0, cnts, gE, bE, x_edges, ev, w_eval, emb, WT + H_ * H_,
      eUb + H_, Vxe, Vx, mask, pS, pAgg, pDen);
  k_red<<<64, 256, 0, stream>>>(pS, pAgg, pDen, Ux, mask, xtmp, sums1, 1);
  // layer 2
  k_node_lin<1><<<BN_, 128, 0, stream>>>(
      x, coord, w_coord, xtmp, sums1, cnts, gN + H_, bN + H_,
      eVw + 2 * H_ * H_, eVb + 2 * H_, nUw + 2 * H_ * H_, nUb + 2 * H_,
      nVw + 2 * H_ * H_, nVb + 2 * H_, mask, Vxe, Ux, Vx);
  k_edge<1, false><<<NBLK_, 256, 0, stream>>>(
      e, etmp, sums1, cnts, gE + H_, bE + H_, x_edges, ev, w_eval, emb,
      WT + 2 * H_ * H_, eUb + 2 * H_, Vxe, Vx, mask, pS, pAgg, pDen);
  k_red<<<64, 256, 0, stream>>>(pS, pAgg, pDen, Ux, mask, xtmp, sums2, 0);
  // head
  k_head<<<NBLK_, 256, 0, stream>>>(e, etmp, sums2, cnts, gE + 2 * H_,
                                    bE + 2 * H_, WT + (size_t)3 * H_ * H_,
                                    mUb, mVw, mVb, mask, (float*)d_out);
}

// Round 15
// 338.276 us; speedup vs baseline: 1.1218x; 1.0076x over previous
//
#include <hip/hip_runtime.h>
#include <hip/hip_bf16.h>

// ConvTSP gated-GCN forward, MI355X (gfx950). Round 15.
// B=4, N=200, H=128, L=3. f32 in/out, x_edges int32.
//
// R14 (340.8us) = best. Final unconfounded A/B: R11 bundled (256,4) with
// rcpf; rcpf alone plausibly caused that regression (trans-pipe
// serialization). (256,4) alone gave VGPR 52, NO spill, clean bytes in
// R11's counters. R15 = R14 byte-identical except k_edge/k_head
// launch_bounds (256,3)->(256,4). Tripwire: bytes>130MB or k_edge>80us
// -> the hint itself is the problem; R14 is final.

typedef __hip_bfloat16 bf16;
typedef __attribute__((ext_vector_type(8))) short short8_t;
typedef __attribute__((ext_vector_type(4))) float f32x4;

#define B_ 4
#define N_ 200
#define H_ 128
#define BN_ (B_ * N_)
#define JT_ 4
#define NBLK_ (BN_ * JT_)
#define MAXROWS_ 64

__device__ __forceinline__ unsigned short f2b(float f) {
  unsigned int i = __float_as_uint(f);
  i = (i + 0x7fffu + ((i >> 16) & 1u)) >> 16;  // RNE
  return (unsigned short)i;
}
__device__ __forceinline__ float b2f16(unsigned short u) {
  return __uint_as_float((unsigned int)u << 16);
}

// ---------------- fused prelude: prep_w | cnt (5 blocks) ----------------

__global__ __launch_bounds__(256) void k_pre(
    const float* __restrict__ eUw, const float* __restrict__ mUw,
    const float* __restrict__ mask, bf16* __restrict__ WT,
    float* __restrict__ cnts) {
  int blk = blockIdx.x, t = threadIdx.x;
  if (blk < 4) {
    const float* src = (blk < 3) ? (eUw + (size_t)blk * H_ * H_) : mUw;
    bf16* dst = WT + (size_t)blk * H_ * H_;
    for (int q = t; q < H_ * H_; q += 256) {
      int out = q >> 7, in = q & 127;
      dst[q] = __float2bfloat16(src[in * H_ + out]);
    }
  } else {
    int b = t >> 6, l = t & 63;
    float s = 0.f;
    for (int n = l; n < N_; n += 64) s += mask[b * N_ + n];
#pragma unroll
    for (int d = 1; d < 64; d <<= 1) s += __shfl_xor(s, d);
    __shared__ float ms[B_];
    if (l == 0) ms[b] = s;
    __syncthreads();
    if (t == 0) {
      float cn = 0.f, ce = 0.f;
      for (int k = 0; k < B_; ++k) { cn += ms[k]; ce += ms[k] * ms[k]; }
      cnts[0] = cn; cnts[1] = ce;
    }
  }
}

// ---------------- node linears (+fused x init/update, inline ssN) --------

template <int UPD>
__global__ __launch_bounds__(128) void k_node_lin(
    float* __restrict__ x, const float* __restrict__ coord,
    const float* __restrict__ w_coord, const float* __restrict__ xtmp,
    const float* __restrict__ sumsPrev, const float* __restrict__ cnts,
    const float* __restrict__ gNp, const float* __restrict__ bNp,
    const float* __restrict__ eVw, const float* __restrict__ eVb,
    const float* __restrict__ nUw, const float* __restrict__ nUb,
    const float* __restrict__ nVw, const float* __restrict__ nVb,
    const float* __restrict__ mask, float* __restrict__ Vxe,
    float* __restrict__ Ux, float* __restrict__ Vx) {
  __shared__ float xr[H_];
  int bi = blockIdx.x, h = threadIdx.x;
  float m = mask[bi];
  float xv;
  if (UPD) {
    xv = x[(size_t)bi * H_ + h];
    float cntN = cnts[0];
    float mN = sumsPrev[256 + h] / cntN;
    float vN = sumsPrev[384 + h] / cntN - mN * mN;
    float scN = gNp[h] * rsqrtf(vN + 1e-5f);
    float shN = bNp[h] - mN * scN;
    float tv = xtmp[(size_t)bi * H_ + h];
    float xn = (m > 0.f) ? fmaf(tv, scN, shN) : tv;
    xv += fmaxf(xn, 0.f);
  } else {
    float c0 = coord[bi * 2 + 0], c1 = coord[bi * 2 + 1];
    xv = c0 * w_coord[h] + c1 * w_coord[H_ + h];
  }
  x[(size_t)bi * H_ + h] = xv;
  xr[h] = xv;
  __syncthreads();
  float a = 0.f, bvv = 0.f, c = 0.f;
#pragma unroll 4
  for (int k = 0; k < H_; ++k) {
    float kx = xr[k];
    a   = fmaf(kx, eVw[k * H_ + h], a);
    bvv = fmaf(kx, nUw[k * H_ + h], bvv);
    c   = fmaf(kx, nVw[k * H_ + h], c);
  }
  Vxe[(size_t)bi * H_ + h] = m * (a + eVb[h]);
  Ux[(size_t)bi * H_ + h]  = m * (bvv + nUb[h]);
  Vx[(size_t)bi * H_ + h]  = m * (c + nVb[h]);
}

// ---------------- big kernel: staged-update + GEMM + epilogue ------------
// grid = BN_*JT_. blockIdx -> (bi, jh). Block owns j-tiles [mt0,mt1).
// MODE 0: layer 0. A = e0 from raw inputs. No e write.
// MODE 2: layer 1. A = e0(recomputed) + relu(bnE(etmp)). Writes e (bf16).
// MODE 1: layer 2. A = e + relu(bnE(etmp)); e updated in place.
// NO global atomics: per-block partials to pS / pAgg / pDen.

template <int MODE, bool DO_X>
__global__ __launch_bounds__(256, 4) void k_edge(
    bf16* __restrict__ e, bf16* __restrict__ etmp,
    const float* __restrict__ sumsPrev, const float* __restrict__ cnts,
    const float* __restrict__ gEp, const float* __restrict__ bEp,
    const int* __restrict__ xe, const float* __restrict__ ev,
    const float* __restrict__ w_eval, const float* __restrict__ emb,
    const bf16* __restrict__ WT, const float* __restrict__ eUb,
    const float* __restrict__ Vxe, const float* __restrict__ Vx,
    const float* __restrict__ mask, float* __restrict__ pS,
    float* __restrict__ pAgg, float* __restrict__ pDen) {
  __shared__ __align__(16) char sA[MAXROWS_ * 256];
  __shared__ float ssE_s[256];
  const int bi = blockIdx.x >> 2;
  const int jh = blockIdx.x & 3;
  const int mt0 = (jh == 0) ? 0 : 3 * jh + 1;
  const int mt1 = 3 * jh + 4;
  const int b = bi / N_;
  const int t = threadIdx.x;
  const int lane = t & 63;
  const int w = t >> 6;
  const float mask_i = mask[bi];

  // inline ssE from previous layer's sums (L2-hot, 2KB)
  if (MODE != 0) {
    int h = t & 127;
    float cntE = cnts[1];
    float mE = sumsPrev[h] / cntE;
    float vE = sumsPrev[128 + h] / cntE - mE * mE;
    float scE = gEp[h] * rsqrtf(vE + 1e-5f);
    ssE_s[t] = (t < 128) ? scE : (bEp[h] - mE * scE);
    __syncthreads();
  }

  // --- B fragments: named, no arrays ---
  const int colA = (w << 5) + (lane & 15);
  const int colB = colA + 16;
  const int kgrp = (lane >> 4) << 3;
  const short* wp0 = (const short*)WT + colA * H_ + kgrp;
  const short* wp1 = (const short*)WT + colB * H_ + kgrp;
  short8_t bfA0 = *(const short8_t*)(wp0);
  short8_t bfA1 = *(const short8_t*)(wp0 + 32);
  short8_t bfA2 = *(const short8_t*)(wp0 + 64);
  short8_t bfA3 = *(const short8_t*)(wp0 + 96);
  short8_t bfB0 = *(const short8_t*)(wp1);
  short8_t bfB1 = *(const short8_t*)(wp1 + 32);
  short8_t bfB2 = *(const short8_t*)(wp1 + 64);
  short8_t bfB3 = *(const short8_t*)(wp1 + 96);

  // --- staging: rows [mt0*16, mt1*16), 8B granule, named scalars ---
  {
    const int nrt = (mt1 - mt0) << 4;  // 48 or 64 rows
    unsigned short* eb = (unsigned short*)e + (size_t)bi * N_ * H_;
    const unsigned short* tb =
        (const unsigned short*)etmp + (size_t)bi * N_ * H_;
    for (int q4 = t; q4 < nrt * 32; q4 += 256) {
      int lr = q4 >> 5, k0 = (q4 & 31) << 2;
      int row = (mt0 << 4) + lr;
      float v0 = 0.f, v1 = 0.f, v2 = 0.f, v3 = 0.f;
      if (row < N_) {
        if (MODE == 0 || MODE == 2) {
          if (k0 < 64) {
            float evv = ev[bi * N_ + row];
            float4 we = *(const float4*)(w_eval + k0);
            v0 = evv * we.x; v1 = evv * we.y;
            v2 = evv * we.z; v3 = evv * we.w;
          } else {
            float4 em4 = *(const float4*)(emb + xe[bi * N_ + row] * 64 + (k0 - 64));
            v0 = em4.x; v1 = em4.y; v2 = em4.z; v3 = em4.w;
          }
        } else {
          ushort4 e4 = *(const ushort4*)(eb + row * H_ + k0);
          v0 = b2f16(e4.x); v1 = b2f16(e4.y);
          v2 = b2f16(e4.z); v3 = b2f16(e4.w);
        }
        if (MODE != 0) {
          ushort4 t4 = *(const ushort4*)(tb + row * H_ + k0);
          float mj = mask[b * N_ + row];
          bool msk = (mask_i * mj) > 0.f;
          float sc0 = ssE_s[k0 + 0], sc1 = ssE_s[k0 + 1];
          float sc2 = ssE_s[k0 + 2], sc3 = ssE_s[k0 + 3];
          float sh0 = ssE_s[128 + k0 + 0], sh1 = ssE_s[128 + k0 + 1];
          float sh2 = ssE_s[128 + k0 + 2], sh3 = ssE_s[128 + k0 + 3];
          float f0 = b2f16(t4.x), f1 = b2f16(t4.y);
          float f2 = b2f16(t4.z), f3 = b2f16(t4.w);
          v0 += fmaxf(msk ? fmaf(f0, sc0, sh0) : f0, 0.f);
          v1 += fmaxf(msk ? fmaf(f1, sc1, sh1) : f1, 0.f);
          v2 += fmaxf(msk ? fmaf(f2, sc2, sh2) : f2, 0.f);
          v3 += fmaxf(msk ? fmaf(f3, sc3, sh3) : f3, 0.f);
        }
      }
      unsigned int p0 = ((unsigned int)f2b(v1) << 16) | f2b(v0);
      unsigned int p1 = ((unsigned int)f2b(v3) << 16) | f2b(v2);
      if (MODE != 0 && row < N_)
        *(uint2*)(eb + row * H_ + k0) = make_uint2(p0, p1);  // persist e_l
      unsigned long long pk = ((unsigned long long)p1 << 32) | p0;
      int byo = (lr << 8) + ((k0 * 2) ^ ((lr & 7) << 4));
      *(unsigned long long*)(sA + byo) = pk;
    }
  }
  __syncthreads();

  // --- GEMM + gate/agg/BN epilogue (R8 shape, no arrays) ---
  const float add0 = eUb[colA] + Vxe[(size_t)bi * H_ + colA];
  const float add1 = eUb[colB] + Vxe[(size_t)bi * H_ + colB];
  const float* VxeB = Vxe + (size_t)b * N_ * H_;
  const float* VxB  = Vx  + (size_t)b * N_ * H_;

  float agg0 = 0.f, agg1 = 0.f, den0 = 0.f, den1 = 0.f;
  float s1a = 0.f, s1b = 0.f, s2a = 0.f, s2b = 0.f;
  const int kb = (lane >> 4) << 4;

  for (int mt = mt0; mt < mt1; ++mt) {
    f32x4 acc0 = {0.f, 0.f, 0.f, 0.f}, acc1 = {0.f, 0.f, 0.f, 0.f};
    int ra = ((mt - mt0) << 4) + (lane & 15);
    const char* ap = sA + (ra << 8);
    int sw = (ra & 7) << 4;
    short8_t av;
    av = *(const short8_t*)(ap + ((kb + 0) ^ sw));
    acc0 = __builtin_amdgcn_mfma_f32_16x16x32_bf16(av, bfA0, acc0, 0, 0, 0);
    acc1 = __builtin_amdgcn_mfma_f32_16x16x32_bf16(av, bfB0, acc1, 0, 0, 0);
    av = *(const short8_t*)(ap + ((kb + 64) ^ sw));
    acc0 = __builtin_amdgcn_mfma_f32_16x16x32_bf16(av, bfA1, acc0, 0, 0, 0);
    acc1 = __builtin_amdgcn_mfma_f32_16x16x32_bf16(av, bfB1, acc1, 0, 0, 0);
    av = *(const short8_t*)(ap + ((kb + 128) ^ sw));
    acc0 = __builtin_amdgcn_mfma_f32_16x16x32_bf16(av, bfA2, acc0, 0, 0, 0);
    acc1 = __builtin_amdgcn_mfma_f32_16x16x32_bf16(av, bfB2, acc1, 0, 0, 0);
    av = *(const short8_t*)(ap + ((kb + 192) ^ sw));
    acc0 = __builtin_amdgcn_mfma_f32_16x16x32_bf16(av, bfA3, acc0, 0, 0, 0);
    acc1 = __builtin_amdgcn_mfma_f32_16x16x32_bf16(av, bfB3, acc1, 0, 0, 0);
#pragma unroll
    for (int r = 0; r < 4; ++r) {
      int j = (mt << 4) + ((lane >> 4) << 2) + r;
      bool valid = (j < N_);
      float mj = valid ? mask[b * N_ + j] : 0.f;
      float sqm = mask_i * mj;
      float vj0 = valid ? VxeB[(size_t)j * H_ + colA] : 0.f;
      float vj1 = valid ? VxeB[(size_t)j * H_ + colB] : 0.f;
      float t0 = acc0[r] + add0 + vj0;
      float t1 = acc1[r] + add1 + vj1;
      if (valid) {
        size_t o = ((size_t)bi * N_ + j) * H_;
        ((unsigned short*)etmp)[o + colA] = f2b(t0);
        ((unsigned short*)etmp)[o + colB] = f2b(t1);
      }
      float g0 = sqm / (1.f + __expf(-t0));
      float g1 = sqm / (1.f + __expf(-t1));
      float vx0 = valid ? VxB[(size_t)j * H_ + colA] : 0.f;
      float vx1 = valid ? VxB[(size_t)j * H_ + colB] : 0.f;
      agg0 = fmaf(g0, vx0, agg0);
      agg1 = fmaf(g1, vx1, agg1);
      den0 += g0; den1 += g1;
      s1a = fmaf(t0, sqm, s1a);
      s1b = fmaf(t1, sqm, s1b);
      s2a = fmaf(t0 * sqm, t0, s2a);
      s2b = fmaf(t1 * sqm, t1, s2b);
    }
  }
#pragma unroll
  for (int d = 16; d <= 32; d <<= 1) {
    agg0 += __shfl_xor(agg0, d); agg1 += __shfl_xor(agg1, d);
    den0 += __shfl_xor(den0, d); den1 += __shfl_xor(den1, d);
    s1a += __shfl_xor(s1a, d);   s1b += __shfl_xor(s1b, d);
    s2a += __shfl_xor(s2a, d);   s2b += __shfl_xor(s2b, d);
  }
  if ((lane >> 4) == 0) {
    float* ps = pS + (size_t)blockIdx.x * 256;
    ps[colA] = s1a;
    ps[colB] = s1b;
    ps[128 + colA] = s2a;
    ps[128 + colB] = s2b;
    if (DO_X) {
      size_t po = ((size_t)jh * BN_ + bi) * H_;
      pAgg[po + colA] = agg0;
      pAgg[po + colB] = agg1;
      pDen[po + colA] = den0;
      pDen[po + colB] = den1;
    }
  }
}

// ---------------- reduce: pS -> BN-E sums; xtmp compute + BN-N sums ------

__global__ __launch_bounds__(256) void k_red(
    const float* __restrict__ pS, const float* __restrict__ pAgg,
    const float* __restrict__ pDen, const float* __restrict__ Ux,
    const float* __restrict__ mask, float* __restrict__ xtmp,
    float* __restrict__ sums, int doN) {
  int g = blockIdx.x, t = threadIdx.x;
  if (g < 32) {
    float acc = 0.f;
    for (int blk = g * (NBLK_ / 32); blk < (g + 1) * (NBLK_ / 32); ++blk)
      acc += pS[(size_t)blk * 256 + t];
    atomicAdd(&sums[t], acc);
  } else if (doN) {
    int g2 = g - 32;
    int col = t & 127;
    bool sq = t >= 128;
    float acc = 0.f;
    for (int bi = g2 * (BN_ / 32); bi < (g2 + 1) * (BN_ / 32); ++bi) {
      float a = pAgg[(size_t)bi * H_ + col] +
                pAgg[((size_t)BN_ + bi) * H_ + col] +
                pAgg[((size_t)2 * BN_ + bi) * H_ + col] +
                pAgg[((size_t)3 * BN_ + bi) * H_ + col];
      float d = pDen[(size_t)bi * H_ + col] +
                pDen[((size_t)BN_ + bi) * H_ + col] +
                pDen[((size_t)2 * BN_ + bi) * H_ + col] +
                pDen[((size_t)3 * BN_ + bi) * H_ + col];
      float xt = Ux[(size_t)bi * H_ + col] + a / (1e-20f + d);
      if (!sq) xtmp[(size_t)bi * H_ + col] = xt;
      float mi = mask[bi];
      acc += (sq ? xt * xt : xt) * mi;
    }
    atomicAdd(&sums[256 + t], acc);
  }
}

// ---------------- head: A = e + relu(bnE(etmp)); y = relu(A@U+bU)@V + bV --

__global__ __launch_bounds__(256, 4) void k_head(
    const bf16* __restrict__ e, const bf16* __restrict__ etmp,
    const float* __restrict__ sumsPrev, const float* __restrict__ cnts,
    const float* __restrict__ gEp, const float* __restrict__ bEp,
    const bf16* __restrict__ UT, const float* __restrict__ Ub,
    const float* __restrict__ Vw, const float* __restrict__ Vb,
    const float* __restrict__ mask, float* __restrict__ y) {
  __shared__ __align__(16) char sA[MAXROWS_ * 256];
  __shared__ float part[4][MAXROWS_][2];
  __shared__ float ssE_s[256];
  const int bi = blockIdx.x >> 2;
  const int jh = blockIdx.x & 3;
  const int mt0 = (jh == 0) ? 0 : 3 * jh + 1;
  const int mt1 = 3 * jh + 4;
  const int b = bi / N_;
  const int t = threadIdx.x;
  const int lane = t & 63;
  const int w = t >> 6;
  const float mask_i = mask[bi];

  {
    int h = t & 127;
    float cntE = cnts[1];
    float mE = sumsPrev[h] / cntE;
    float vE = sumsPrev[128 + h] / cntE - mE * mE;
    float scE = gEp[h] * rsqrtf(vE + 1e-5f);
    ssE_s[t] = (t < 128) ? scE : (bEp[h] - mE * scE);
    __syncthreads();
  }

  const int colA = (w << 5) + (lane & 15);
  const int colB = colA + 16;
  const int kgrp = (lane >> 4) << 3;
  const short* wp0 = (const short*)UT + colA * H_ + kgrp;
  const short* wp1 = (const short*)UT + colB * H_ + kgrp;
  short8_t bfA0 = *(const short8_t*)(wp0);
  short8_t bfA1 = *(const short8_t*)(wp0 + 32);
  short8_t bfA2 = *(const short8_t*)(wp0 + 64);
  short8_t bfA3 = *(const short8_t*)(wp0 + 96);
  short8_t bfB0 = *(const short8_t*)(wp1);
  short8_t bfB1 = *(const short8_t*)(wp1 + 32);
  short8_t bfB2 = *(const short8_t*)(wp1 + 64);
  short8_t bfB3 = *(const short8_t*)(wp1 + 96);

  {
    const int nrt = (mt1 - mt0) << 4;
    const unsigned short* eb = (const unsigned short*)e + (size_t)bi * N_ * H_;
    const unsigned short* tb =
        (const unsigned short*)etmp + (size_t)bi * N_ * H_;
    for (int q4 = t; q4 < nrt * 32; q4 += 256) {
      int lr = q4 >> 5, k0 = (q4 & 31) << 2;
      int row = (mt0 << 4) + lr;
      float v0 = 0.f, v1 = 0.f, v2 = 0.f, v3 = 0.f;
      if (row < N_) {
        ushort4 e4 = *(const ushort4*)(eb + row * H_ + k0);
        ushort4 t4 = *(const ushort4*)(tb + row * H_ + k0);
        float mj = mask[b * N_ + row];
        bool msk = (mask_i * mj) > 0.f;
        float sc0 = ssE_s[k0 + 0], sc1 = ssE_s[k0 + 1];
        float sc2 = ssE_s[k0 + 2], sc3 = ssE_s[k0 + 3];
        float sh0 = ssE_s[128 + k0 + 0], sh1 = ssE_s[128 + k0 + 1];
        float sh2 = ssE_s[128 + k0 + 2], sh3 = ssE_s[128 + k0 + 3];
        float f0 = b2f16(t4.x), f1 = b2f16(t4.y);
        float f2 = b2f16(t4.z), f3 = b2f16(t4.w);
        v0 = b2f16(e4.x) + fmaxf(msk ? fmaf(f0, sc0, sh0) : f0, 0.f);
        v1 = b2f16(e4.y) + fmaxf(msk ? fmaf(f1, sc1, sh1) : f1, 0.f);
        v2 = b2f16(e4.z) + fmaxf(msk ? fmaf(f2, sc2, sh2) : f2, 0.f);
        v3 = b2f16(e4.w) + fmaxf(msk ? fmaf(f3, sc3, sh3) : f3, 0.f);
      }
      unsigned int p0 = ((unsigned int)f2b(v1) << 16) | f2b(v0);
      unsigned int p1 = ((unsigned int)f2b(v3) << 16) | f2b(v2);
      unsigned long long pk = ((unsigned long long)p1 << 32) | p0;
      int byo = (lr << 8) + ((k0 * 2) ^ ((lr & 7) << 4));
      *(unsigned long long*)(sA + byo) = pk;
    }
  }
  __syncthreads();

  float bu0 = Ub[colA], bu1 = Ub[colB];
  float v00 = Vw[colA * 2], v01 = Vw[colA * 2 + 1];
  float v10 = Vw[colB * 2], v11 = Vw[colB * 2 + 1];
  const int kb = (lane >> 4) << 4;

  for (int mt = mt0; mt < mt1; ++mt) {
    f32x4 acc0 = {0.f, 0.f, 0.f, 0.f}, acc1 = {0.f, 0.f, 0.f, 0.f};
    int ra = ((mt - mt0) << 4) + (lane & 15);
    const char* ap = sA + (ra << 8);
    int sw = (ra & 7) << 4;
    short8_t av;
    av = *(const short8_t*)(ap + ((kb + 0) ^ sw));
    acc0 = __builtin_amdgcn_mfma_f32_16x16x32_bf16(av, bfA0, acc0, 0, 0, 0);
    acc1 = __builtin_amdgcn_mfma_f32_16x16x32_bf16(av, bfB0, acc1, 0, 0, 0);
    av = *(const short8_t*)(ap + ((kb + 64) ^ sw));
    acc0 = __builtin_amdgcn_mfma_f32_16x16x32_bf16(av, bfA1, acc0, 0, 0, 0);
    acc1 = __builtin_amdgcn_mfma_f32_16x16x32_bf16(av, bfB1, acc1, 0, 0, 0);
    av = *(const short8_t*)(ap + ((kb + 128) ^ sw));
    acc0 = __builtin_amdgcn_mfma_f32_16x16x32_bf16(av, bfA2, acc0, 0, 0, 0);
    acc1 = __builtin_amdgcn_mfma_f32_16x16x32_bf16(av, bfB2, acc1, 0, 0, 0);
    av = *(const short8_t*)(ap + ((kb + 192) ^ sw));
    acc0 = __builtin_amdgcn_mfma_f32_16x16x32_bf16(av, bfA3, acc0, 0, 0, 0);
    acc1 = __builtin_amdgcn_mfma_f32_16x16x32_bf16(av, bfB3, acc1, 0, 0, 0);
#pragma unroll
    for (int r = 0; r < 4; ++r) {
      float h0v = fmaxf(acc0[r] + bu0, 0.f);
      float h1v = fmaxf(acc1[r] + bu1, 0.f);
      float p0 = h0v * v00 + h1v * v10;
      float p1 = h0v * v01 + h1v * v11;
#pragma unroll
      for (int d = 1; d < 16; d <<= 1) {
        p0 += __shfl_xor(p0, d);
        p1 += __shfl_xor(p1, d);
      }
      int jl = ((mt - mt0) << 4) + ((lane >> 4) << 2) + r;
      if ((lane & 15) == 0) { part[w][jl][0] = p0; part[w][jl][1] = p1; }
    }
  }
  __syncthreads();
  float vb0 = Vb[0], vb1 = Vb[1];
  const int nrt = (mt1 - mt0) << 4;
  for (int q = t; q < nrt * 2; q += 256) {
    int jl = q >> 1, c = q & 1;
    int j = (mt0 << 4) + jl;
    if (j < N_) {
      float s = part[0][jl][c] + part[1][jl][c] + part[2][jl][c] +
                part[3][jl][c] + (c ? vb1 : vb0);
      y[((size_t)bi * N_ + j) * 2 + c] = s;
    }
  }
}

// ---------------- launch ----------------

extern "C" void kernel_launch(void* const* d_in, const int* in_sizes, int n_in,
                              void* d_out, int out_size, void* d_ws,
                              size_t ws_size, hipStream_t stream) {
  const int*   x_edges = (const int*)d_in[0];
  const float* ev      = (const float*)d_in[1];
  const float* coord   = (const float*)d_in[2];
  const float* mask    = (const float*)d_in[3];
  const float* w_coord = (const float*)d_in[4];
  const float* w_eval  = (const float*)d_in[5];
  const float* emb     = (const float*)d_in[6];
  const float* eUw = (const float*)d_in[7];
  const float* eUb = (const float*)d_in[8];
  const float* eVw = (const float*)d_in[9];
  const float* eVb = (const float*)d_in[10];
  const float* nUw = (const float*)d_in[11];
  const float* nUb = (const float*)d_in[12];
  const float* nVw = (const float*)d_in[13];
  const float* nVb = (const float*)d_in[14];
  const float* gE  = (const float*)d_in[15];
  const float* bE  = (const float*)d_in[16];
  const float* gN  = (const float*)d_in[17];
  const float* bN  = (const float*)d_in[18];
  const float* mUw = (const float*)d_in[19];
  const float* mUb = (const float*)d_in[20];
  const float* mVw = (const float*)d_in[21];
  const float* mVb = (const float*)d_in[22];

  char* ws = (char*)d_ws;
  size_t off = 0;
  auto alloc = [&](size_t bytes) {
    void* p = ws + off;
    off += (bytes + 255) & ~(size_t)255;
    return p;
  };
  bf16* e     = (bf16*)alloc((size_t)B_ * N_ * N_ * H_ * 2);   // 40.96 MB
  bf16* etmp  = (bf16*)alloc((size_t)B_ * N_ * N_ * H_ * 2);   // 40.96 MB
  float* x    = (float*)alloc((size_t)BN_ * H_ * 4);
  float* Vxe  = (float*)alloc((size_t)BN_ * H_ * 4);
  float* Ux   = (float*)alloc((size_t)BN_ * H_ * 4);
  float* Vx   = (float*)alloc((size_t)BN_ * H_ * 4);
  float* xtmp = (float*)alloc((size_t)BN_ * H_ * 4);
  float* pS   = (float*)alloc((size_t)NBLK_ * 256 * 4);        // 3.28 MB
  float* pAgg = (float*)alloc((size_t)JT_ * BN_ * H_ * 4);     // 1.64 MB
  float* pDen = (float*)alloc((size_t)JT_ * BN_ * H_ * 4);     // 1.64 MB
  float* sums = (float*)alloc(3 * 512 * 4);  // 3 layers x [s1E,s2E,s1N,s2N]
  float* cnts = (float*)alloc(256);
  bf16* WT    = (bf16*)alloc((size_t)4 * H_ * H_ * 2);

  hipMemsetAsync(sums, 0, 3 * 512 * 4, stream);
  k_pre<<<5, 256, 0, stream>>>(eUw, mUw, mask, WT, cnts);

  float* sums0 = sums;
  float* sums1 = sums + 512;
  float* sums2 = sums + 1024;

  // layer 0
  k_node_lin<0><<<BN_, 128, 0, stream>>>(
      x, coord, w_coord, xtmp, sums0, cnts, gN, bN, eVw, eVb, nUw, nUb, nVw,
      nVb, mask, Vxe, Ux, Vx);
  k_edge<0, true><<<NBLK_, 256, 0, stream>>>(
      e, etmp, sums0, cnts, gE, bE, x_edges, ev, w_eval, emb, WT, eUb, Vxe,
      Vx, mask, pS, pAgg, pDen);
  k_red<<<64, 256, 0, stream>>>(pS, pAgg, pDen, Ux, mask, xtmp, sums0, 1);
  // layer 1
  k_node_lin<1><<<BN_, 128, 0, stream>>>(
      x, coord, w_coord, xtmp, sums0, cnts, gN, bN, eVw + H_ * H_, eVb + H_,
      nUw + H_ * H_, nUb + H_, nVw + H_ * H_, nVb + H_, mask, Vxe, Ux, Vx);
  k_edge<2, true><<<NBLK_, 256, 0, stream>>>(
      e, etmp, sums0, cnts, gE, bE, x_edges, ev, w_eval, emb, WT + H_ * H_,
      eUb + H_, Vxe, Vx, mask, pS, pAgg, pDen);
  k_red<<<64, 256, 0, stream>>>(pS, pAgg, pDen, Ux, mask, xtmp, sums1, 1);
  // layer 2
  k_node_lin<1><<<BN_, 128, 0, stream>>>(
      x, coord, w_coord, xtmp, sums1, cnts, gN + H_, bN + H_,
      eVw + 2 * H_ * H_, eVb + 2 * H_, nUw + 2 * H_ * H_, nUb + 2 * H_,
      nVw + 2 * H_ * H_, nVb + 2 * H_, mask, Vxe, Ux, Vx);
  k_edge<1, false><<<NBLK_, 256, 0, stream>>>(
      e, etmp, sums1, cnts, gE + H_, bE + H_, x_edges, ev, w_eval, emb,
      WT + 2 * H_ * H_, eUb + 2 * H_, Vxe, Vx, mask, pS, pAgg, pDen);
  k_red<<<64, 256, 0, stream>>>(pS, pAgg, pDen, Ux, mask, xtmp, sums2, 0);
  // head
  k_head<<<NBLK_, 256, 0, stream>>>(e, etmp, sums2, cnts, gE + 2 * H_,
                                    bE + 2 * H_, WT + (size_t)3 * H_ * H_,
                                    mUb, mVw, mVb, mask, (float*)d_out);
}